// Round 1
// baseline (941.904 us; speedup 1.0000x reference)
//
#include <hip/hip_runtime.h>
#include <hip/hip_bf16.h>

// Mixer2dTriUKAN forward.
//
// Key simplifications vs the reference:
//  * gcn_spatial uses a = softmax(P, axis=-1) ONLY through sum(a, axis=-1),
//    which is identically 1.0  =>  x1 == x2 == x. The whole FFT /
//    prob_distance / A1 / A2 pipeline is dead code and is skipped.
//  * concat([x,x,x]) @ g_w.T  ==  x @ (g_w[:, :512]+g_w[:, 512:1024]+g_w[:, 1024:]).T
//
// Shapes: B=16, C4=128, T=D=512, H=64, K=8 spline bases (+silu => 9 features).
// M = B*C4 = 2048 rows everywhere; all "KAN" layers are feature-expansion
// (x -> 9 features per input element) followed by an NT GEMM.

#define M_ROWS 2048
#define TDIM   512
#define C4DIM  128
#define HDIM   64
#define NFEAT  9

// ---------------------------------------------------------------------------
// math helpers
// ---------------------------------------------------------------------------
__device__ __forceinline__ float siluf(float v) {
    return v / (1.0f + __expf(-v));
}
__device__ __forceinline__ float geluf(float v) {
    return 0.5f * v * (1.0f + erff(v * 0.70710678118654752440f));
}

// Cox-de Boor cubic B-spline bases on uniform grid g[i] = (i-3)*0.4 - 1, i=0..11
// f[0] = silu(v), f[1..8] = 8 cubic bases. Matches the reference recursion.
__device__ __forceinline__ void features9(float v, float* f) {
    f[0] = siluf(v);
    float b[11];
#pragma unroll
    for (int i = 0; i < 11; ++i) {
        float gi  = (float)(i - 3) * 0.4f - 1.0f;
        float gi1 = (float)(i - 2) * 0.4f - 1.0f;
        b[i] = (v >= gi && v < gi1) ? 1.0f : 0.0f;
    }
#pragma unroll
    for (int k = 1; k <= 3; ++k) {
#pragma unroll
        for (int i = 0; i + k < 11; ++i) {
            float gi   = (float)(i - 3) * 0.4f - 1.0f;
            float gi1  = (float)(i - 2) * 0.4f - 1.0f;
            float gik  = (float)(i + k - 3) * 0.4f - 1.0f;
            float gik1 = (float)(i + k - 2) * 0.4f - 1.0f;
            float inv_a = 1.0f / (gik - gi);    // compile-time constants
            float inv_b = 1.0f / (gik1 - gi1);
            b[i] = (v - gi) * inv_a * b[i] + (gik1 - v) * inv_b * b[i + 1];
        }
    }
#pragma unroll
    for (int k = 0; k < 8; ++k) f[1 + k] = b[k];
}

// ---------------------------------------------------------------------------
// small builder kernels
// ---------------------------------------------------------------------------

// Weff[o, i] = gw[o, i] + gw[o, 512+i] + gw[o, 1024+i]    (512 x 512 from 512 x 1536)
__global__ void build_weff(const float* __restrict__ gw, float* __restrict__ weff) {
    int idx = blockIdx.x * blockDim.x + threadIdx.x;   // 0 .. 512*512-1
    int o = idx >> 9, i = idx & 511;
    const float* r = gw + (size_t)o * 1536;
    weff[idx] = r[i] + r[512 + i] + r[1024 + i];
}

// Wcat[o][j][i], j=0..8: j==0 -> base_w[o,i]; j==1+k -> spline_w[o,i,k]
__global__ void build_wcat(const float* __restrict__ base_w, const float* __restrict__ spline_w,
                           float* __restrict__ wcat, int O, int I) {
    int idx = blockIdx.x * blockDim.x + threadIdx.x;   // 0 .. O*I-1
    if (idx >= O * I) return;
    int o = idx / I, i = idx - o * I;
    float* w = wcat + (size_t)o * NFEAT * I;
    w[i] = base_w[idx];
    const float* sp = spline_w + (size_t)idx * 8;
#pragma unroll
    for (int k = 0; k < 8; ++k) w[(1 + k) * I + i] = sp[k];
}

// per-batch mean / rstd over 65536 elements (joint LayerNorm over (L, C))
__global__ void stats_kernel(const float* __restrict__ X, float* __restrict__ mu,
                             float* __restrict__ rstd) {
    __shared__ float ssum[256], ssq[256];
    int b = blockIdx.x;
    const float* p = X + (size_t)b * (C4DIM * TDIM);
    float s = 0.f, q = 0.f;
    for (int i = threadIdx.x; i < C4DIM * TDIM; i += 256) {
        float v = p[i];
        s += v; q = fmaf(v, v, q);
    }
    ssum[threadIdx.x] = s; ssq[threadIdx.x] = q;
    __syncthreads();
    for (int off = 128; off > 0; off >>= 1) {
        if (threadIdx.x < off) {
            ssum[threadIdx.x] += ssum[threadIdx.x + off];
            ssq[threadIdx.x]  += ssq[threadIdx.x + off];
        }
        __syncthreads();
    }
    if (threadIdx.x == 0) {
        float m   = ssum[0] * (1.0f / 65536.0f);
        float var = ssq[0] * (1.0f / 65536.0f) - m * m;
        mu[b]   = m;
        rstd[b] = rsqrtf(var + 1e-5f);
    }
}

// FEAT[m][j][i] (I=512, Kd=4608) from X (2048 x 512); optional fused LayerNorm.
// LN: v = (x - mu[b]) * rstd[b] * lnw[l*128+c] + lnb[l*128+c],  m = b*128 + c, l = i
template<bool LN>
__global__ void build_feat(const float* __restrict__ X, const float* __restrict__ stats,
                           const float* __restrict__ lnw, const float* __restrict__ lnb,
                           float* __restrict__ FEAT) {
    int i = blockIdx.x * blockDim.x + threadIdx.x;   // 0..511
    int m = blockIdx.y;                              // 0..2047
    float v = X[(size_t)m * TDIM + i];
    if (LN) {
        int b = m >> 7, c = m & 127;
        v = (v - stats[b]) * stats[16 + b] * lnw[i * C4DIM + c] + lnb[i * C4DIM + c];
    }
    float f[NFEAT];
    features9(v, f);
    float* out = FEAT + (size_t)m * (NFEAT * TDIM) + i;
#pragma unroll
    for (int j = 0; j < NFEAT; ++j) out[j * TDIM] = f[j];
}

// reduce 8 split-K partials (PART[z][m][64]) -> h1, then FEAT2[m][j][i] (I=64, Kd=576)
__global__ void build_feat2(const float* __restrict__ PART, float* __restrict__ FEAT2) {
    int idx = blockIdx.x * blockDim.x + threadIdx.x;  // 0 .. 2048*64-1
    int m = idx >> 6, i = idx & 63;
    float h = 0.f;
#pragma unroll
    for (int z = 0; z < 8; ++z) h += PART[((size_t)z * M_ROWS + m) * HDIM + i];
    float f[NFEAT];
    features9(h, f);
    float* out = FEAT2 + (size_t)m * (NFEAT * HDIM) + i;
#pragma unroll
    for (int j = 0; j < NFEAT; ++j) out[j * HDIM] = f[j];
}

// ---------------------------------------------------------------------------
// f32 NT GEMM:  C[m,n] = sum_k A[m*Kd+k] * B[n*Kd+k]
// 64x64 tile, BK=16, 256 threads, 4x4 per thread.
// EPI: 0 plain store (supports split-K via blockIdx.z offset)
//      1 C = aux[m*N+n] + acc        (residual add)
//      2 C = gelu(acc + aux[n])      (bias + erf-GELU)
//      3 C[m*N+n] += acc             (accumulate into existing output)
// ---------------------------------------------------------------------------
template<int EPI>
__global__ __launch_bounds__(256)
void gemm_nt(const float* __restrict__ A, const float* __restrict__ B,
             float* __restrict__ C, const float* __restrict__ aux,
             int M, int N, int Kd, int kPerZ) {
    __shared__ __align__(16) float As[16][68];
    __shared__ __align__(16) float Bs[16][68];
    const int bm = blockIdx.y * 64;
    const int bn = blockIdx.x * 64;
    const int k0 = blockIdx.z * kPerZ;
    const int tid = threadIdx.x;
    const int tm = (tid >> 4) << 2;   // 0,4,...,60
    const int tn = (tid & 15) << 2;   // 0,4,...,60
    const int lrow = tid >> 2;        // 0..63
    const int lk4  = (tid & 3) << 2;  // 0,4,8,12

    const float* Ablk = A + (size_t)bm * Kd;
    const float* Bblk = B + (size_t)bn * Kd;

    float acc[4][4] = {};

    for (int kt = 0; kt < kPerZ; kt += 16) {
        float4 a4 = *reinterpret_cast<const float4*>(Ablk + (size_t)lrow * Kd + k0 + kt + lk4);
        float4 b4 = *reinterpret_cast<const float4*>(Bblk + (size_t)lrow * Kd + k0 + kt + lk4);
        __syncthreads();
        As[lk4 + 0][lrow] = a4.x; As[lk4 + 1][lrow] = a4.y;
        As[lk4 + 2][lrow] = a4.z; As[lk4 + 3][lrow] = a4.w;
        Bs[lk4 + 0][lrow] = b4.x; Bs[lk4 + 1][lrow] = b4.y;
        Bs[lk4 + 2][lrow] = b4.z; Bs[lk4 + 3][lrow] = b4.w;
        __syncthreads();
#pragma unroll
        for (int k = 0; k < 16; ++k) {
            float4 av = *reinterpret_cast<const float4*>(&As[k][tm]);
            float4 bv = *reinterpret_cast<const float4*>(&Bs[k][tn]);
            acc[0][0] = fmaf(av.x, bv.x, acc[0][0]);
            acc[0][1] = fmaf(av.x, bv.y, acc[0][1]);
            acc[0][2] = fmaf(av.x, bv.z, acc[0][2]);
            acc[0][3] = fmaf(av.x, bv.w, acc[0][3]);
            acc[1][0] = fmaf(av.y, bv.x, acc[1][0]);
            acc[1][1] = fmaf(av.y, bv.y, acc[1][1]);
            acc[1][2] = fmaf(av.y, bv.z, acc[1][2]);
            acc[1][3] = fmaf(av.y, bv.w, acc[1][3]);
            acc[2][0] = fmaf(av.z, bv.x, acc[2][0]);
            acc[2][1] = fmaf(av.z, bv.y, acc[2][1]);
            acc[2][2] = fmaf(av.z, bv.z, acc[2][2]);
            acc[2][3] = fmaf(av.z, bv.w, acc[2][3]);
            acc[3][0] = fmaf(av.w, bv.x, acc[3][0]);
            acc[3][1] = fmaf(av.w, bv.y, acc[3][1]);
            acc[3][2] = fmaf(av.w, bv.z, acc[3][2]);
            acc[3][3] = fmaf(av.w, bv.w, acc[3][3]);
        }
    }

    float* Cz = C + (size_t)blockIdx.z * M * N;
#pragma unroll
    for (int ii = 0; ii < 4; ++ii) {
        int row = bm + tm + ii;
        size_t off = (size_t)row * N + bn + tn;
        if (EPI == 0) {
            *reinterpret_cast<float4*>(Cz + off) =
                make_float4(acc[ii][0], acc[ii][1], acc[ii][2], acc[ii][3]);
        } else if (EPI == 1) {
            float4 r = *reinterpret_cast<const float4*>(aux + off);
            *reinterpret_cast<float4*>(C + off) =
                make_float4(acc[ii][0] + r.x, acc[ii][1] + r.y,
                            acc[ii][2] + r.z, acc[ii][3] + r.w);
        } else if (EPI == 2) {
            float4 t;
            t.x = geluf(acc[ii][0] + aux[bn + tn + 0]);
            t.y = geluf(acc[ii][1] + aux[bn + tn + 1]);
            t.z = geluf(acc[ii][2] + aux[bn + tn + 2]);
            t.w = geluf(acc[ii][3] + aux[bn + tn + 3]);
            *reinterpret_cast<float4*>(C + off) = t;
        } else {  // EPI == 3
            float4 cur = *reinterpret_cast<float4*>(C + off);
            *reinterpret_cast<float4*>(C + off) =
                make_float4(cur.x + acc[ii][0], cur.y + acc[ii][1],
                            cur.z + acc[ii][2], cur.w + acc[ii][3]);
        }
    }
}

// ---------------------------------------------------------------------------
// launch
// ---------------------------------------------------------------------------
extern "C" void kernel_launch(void* const* d_in, const int* in_sizes, int n_in,
                              void* d_out, int out_size, void* d_ws, size_t ws_size,
                              hipStream_t stream) {
    const float* x            = (const float*)d_in[0];
    const float* tm1_ln_w     = (const float*)d_in[1];
    const float* tm1_ln_b     = (const float*)d_in[2];
    const float* tm1_k1_base  = (const float*)d_in[3];
    const float* tm1_k1_spl   = (const float*)d_in[4];
    const float* tm1_k2_base  = (const float*)d_in[5];
    const float* tm1_k2_spl   = (const float*)d_in[6];
    // d_in[7] = A1   (dead code: sum(softmax)==1)
    const float* g1_w         = (const float*)d_in[8];
    const float* g1_b         = (const float*)d_in[9];
    const float* k1_base      = (const float*)d_in[10];
    const float* k1_spl       = (const float*)d_in[11];
    const float* tm_ln_w      = (const float*)d_in[12];
    const float* tm_ln_b      = (const float*)d_in[13];
    const float* tm_k1_base   = (const float*)d_in[14];
    const float* tm_k1_spl    = (const float*)d_in[15];
    const float* tm_k2_base   = (const float*)d_in[16];
    const float* tm_k2_spl    = (const float*)d_in[17];
    // d_in[18] = A2  (dead)
    const float* g2_w         = (const float*)d_in[19];
    const float* g2_b         = (const float*)d_in[20];
    const float* k2_base      = (const float*)d_in[21];
    const float* k2_spl       = (const float*)d_in[22];

    float* out = (float*)d_out;
    float* ws  = (float*)d_ws;

    // workspace layout (floats); total ~71.3 MB
    float* FEAT  = ws;                         // 2048*4608
    float* FEAT2 = FEAT  + (size_t)M_ROWS * 4608;   // 2048*576
    float* PART  = FEAT2 + (size_t)M_ROWS * 576;    // 8*2048*64
    float* BUF1  = PART  + (size_t)8 * M_ROWS * 64; // 2048*512 (TM1 then TM)
    float* BUF2  = BUF1  + (size_t)M_ROWS * 512;    // 2048*512 (CM then Y2)
    float* W1a   = BUF2  + (size_t)M_ROWS * 512;    // 64*4608
    float* W1b   = W1a   + (size_t)64 * 4608;
    float* W2a   = W1b   + (size_t)64 * 4608;       // 512*576
    float* W2b   = W2a   + (size_t)512 * 576;
    float* WE1   = W2b   + (size_t)512 * 576;       // 512*512
    float* WE2   = WE1   + (size_t)512 * 512;
    float* KX    = WE2   + (size_t)512 * 512;       // 512*4608
    float* STATS = KX    + (size_t)512 * 4608;      // 64

    // ---- weight preprocessing -------------------------------------------
    build_weff<<<1024, 256, 0, stream>>>(g1_w, WE1);
    build_weff<<<1024, 256, 0, stream>>>(g2_w, WE2);
    build_wcat<<<128,  256, 0, stream>>>(tm1_k1_base, tm1_k1_spl, W1a, 64, 512);
    build_wcat<<<128,  256, 0, stream>>>(tm_k1_base,  tm_k1_spl,  W1b, 64, 512);
    build_wcat<<<128,  256, 0, stream>>>(tm1_k2_base, tm1_k2_spl, W2a, 512, 64);
    build_wcat<<<128,  256, 0, stream>>>(tm_k2_base,  tm_k2_spl,  W2b, 512, 64);
    build_wcat<<<1024, 256, 0, stream>>>(k1_base, k1_spl, KX, 512, 512);

    // ---- branch 1: tm1 = token_mixing(x); y1 = gelu(tm1 @ WE1 + b1) -> out
    stats_kernel<<<16, 256, 0, stream>>>(x, STATS, STATS + 16);
    build_feat<true><<<dim3(2, M_ROWS), 256, 0, stream>>>(x, STATS, tm1_ln_w, tm1_ln_b, FEAT);
    gemm_nt<0><<<dim3(1, 32, 8), 256, 0, stream>>>(FEAT, W1a, PART, nullptr, M_ROWS, 64, 4608, 576);
    build_feat2<<<512, 256, 0, stream>>>(PART, FEAT2);
    gemm_nt<1><<<dim3(8, 32, 1), 256, 0, stream>>>(FEAT2, W2a, BUF1, x, M_ROWS, 512, 576, 576);
    gemm_nt<2><<<dim3(8, 32, 1), 256, 0, stream>>>(BUF1, WE1, out, g1_b, M_ROWS, 512, 512, 512);

    // ---- branch 2: cm = kan(x); tm = token_mixing(cm); y2 = gelu(...); z = kan(y2)
    build_feat<false><<<dim3(2, M_ROWS), 256, 0, stream>>>(x, nullptr, nullptr, nullptr, FEAT);
    gemm_nt<0><<<dim3(8, 32, 1), 256, 0, stream>>>(FEAT, KX, BUF2, nullptr, M_ROWS, 512, 4608, 4608);

    stats_kernel<<<16, 256, 0, stream>>>(BUF2, STATS + 32, STATS + 48);
    build_feat<true><<<dim3(2, M_ROWS), 256, 0, stream>>>(BUF2, STATS + 32, tm_ln_w, tm_ln_b, FEAT);
    gemm_nt<0><<<dim3(1, 32, 8), 256, 0, stream>>>(FEAT, W1b, PART, nullptr, M_ROWS, 64, 4608, 576);
    build_feat2<<<512, 256, 0, stream>>>(PART, FEAT2);
    gemm_nt<1><<<dim3(8, 32, 1), 256, 0, stream>>>(FEAT2, W2b, BUF1, BUF2, M_ROWS, 512, 576, 576);
    gemm_nt<2><<<dim3(8, 32, 1), 256, 0, stream>>>(BUF1, WE2, BUF2, g2_b, M_ROWS, 512, 512, 512);

    build_wcat<<<1024, 256, 0, stream>>>(k2_base, k2_spl, KX, 512, 512);
    build_feat<false><<<dim3(2, M_ROWS), 256, 0, stream>>>(BUF2, nullptr, nullptr, nullptr, FEAT);
    gemm_nt<3><<<dim3(8, 32, 1), 256, 0, stream>>>(FEAT, KX, out, nullptr, M_ROWS, 512, 4608, 4608);
}

// Round 2
// 553.494 us; speedup vs baseline: 1.7017x; 1.7017x over previous
//
#include <hip/hip_runtime.h>
#include <hip/hip_bf16.h>

// Mixer2dTriUKAN forward — bf16 MFMA version.
//
// Algebraic simplifications (verified correct in round 1):
//  * sum(softmax(P),-1) == 1  =>  prob_distance/FFT pipeline is dead code.
//  * concat([x,x,x]) @ g_w.T == x @ (sum of the three 512-col blocks).T
//
// All GEMMs are NT (A: MxK row-major, B: NxK row-major) and run on
// v_mfma_f32_16x16x32_bf16 with f32 accumulation. Activations/weights bf16.

#define M_ROWS 2048
#define TDIM   512
#define C4DIM  128
#define NFEAT  9

typedef unsigned short u16;
typedef __attribute__((ext_vector_type(8))) short short8;
typedef __attribute__((ext_vector_type(4))) float f32x4;

// ---------------------------------------------------------------------------
// helpers
// ---------------------------------------------------------------------------
__device__ __forceinline__ float bf2f(u16 u) {
    union { unsigned int i; float f; } c; c.i = ((unsigned int)u) << 16; return c.f;
}
__device__ __forceinline__ u16 f2bf(float v) {
    __hip_bfloat16 h = __float2bfloat16(v);
    return *reinterpret_cast<u16*>(&h);
}
__device__ __forceinline__ float siluf(float v) { return v / (1.0f + __expf(-v)); }
__device__ __forceinline__ float geluf(float v) {
    return 0.5f * v * (1.0f + erff(v * 0.70710678118654752440f));
}

// silu + 8 cubic B-spline bases on uniform grid g[i] = (i-3)*0.4 - 1
__device__ __forceinline__ void features9(float v, float* f) {
    f[0] = siluf(v);
    float b[11];
#pragma unroll
    for (int i = 0; i < 11; ++i) {
        float gi  = (float)(i - 3) * 0.4f - 1.0f;
        float gi1 = (float)(i - 2) * 0.4f - 1.0f;
        b[i] = (v >= gi && v < gi1) ? 1.0f : 0.0f;
    }
#pragma unroll
    for (int k = 1; k <= 3; ++k) {
#pragma unroll
        for (int i = 0; i + k < 11; ++i) {
            float gi   = (float)(i - 3) * 0.4f - 1.0f;
            float gi1  = (float)(i - 2) * 0.4f - 1.0f;
            float gik  = (float)(i + k - 3) * 0.4f - 1.0f;
            float gik1 = (float)(i + k - 2) * 0.4f - 1.0f;
            b[i] = (v - gi) * (1.0f / (gik - gi)) * b[i]
                 + (gik1 - v) * (1.0f / (gik1 - gi1)) * b[i + 1];
        }
    }
#pragma unroll
    for (int k = 0; k < 8; ++k) f[1 + k] = b[k];
}

// ---------------------------------------------------------------------------
// builder kernels
// ---------------------------------------------------------------------------

// Weff[o,i] = sum of three 512-blocks of gw row o -> bf16
__global__ void build_weff(const float* __restrict__ gw, u16* __restrict__ weff) {
    int idx = blockIdx.x * blockDim.x + threadIdx.x;   // 512*512
    int o = idx >> 9, i = idx & 511;
    const float* r = gw + (size_t)o * 1536;
    weff[idx] = f2bf(r[i] + r[512 + i] + r[1024 + i]);
}

// Wcat[o][j*I+i]: j==0 base_w[o,i]; j==1+k spline_w[o,i,k] -> bf16
__global__ void build_wcat(const float* __restrict__ base_w, const float* __restrict__ spline_w,
                           u16* __restrict__ wcat, int O, int I) {
    int idx = blockIdx.x * blockDim.x + threadIdx.x;   // O*I
    if (idx >= O * I) return;
    int o = idx / I, i = idx - o * I;
    u16* w = wcat + (size_t)o * NFEAT * I;
    w[i] = f2bf(base_w[idx]);
    const float* sp = spline_w + (size_t)idx * 8;
#pragma unroll
    for (int k = 0; k < 8; ++k) w[(1 + k) * I + i] = f2bf(sp[k]);
}

// x (f32) -> bf16 copy (for residual aux)
__global__ void convert_f2bf(const float* __restrict__ in, u16* __restrict__ out) {
    int idx = (blockIdx.x * blockDim.x + threadIdx.x) * 4;
    float4 v = *reinterpret_cast<const float4*>(in + idx);
    ushort4 o; o.x = f2bf(v.x); o.y = f2bf(v.y); o.z = f2bf(v.z); o.w = f2bf(v.w);
    *reinterpret_cast<ushort4*>(out + idx) = o;
}

// per-batch mean / rstd over 65536 elements; input f32 or bf16
template<bool INBF>
__global__ void stats_kernel(const void* __restrict__ X, float* __restrict__ mu,
                             float* __restrict__ rstd) {
    __shared__ float ssum[256], ssq[256];
    int b = blockIdx.x;
    float s = 0.f, q = 0.f;
    if (INBF) {
        const u16* p = (const u16*)X + (size_t)b * (C4DIM * TDIM);
        for (int i = threadIdx.x; i < C4DIM * TDIM; i += 256) {
            float v = bf2f(p[i]); s += v; q = fmaf(v, v, q);
        }
    } else {
        const float* p = (const float*)X + (size_t)b * (C4DIM * TDIM);
        for (int i = threadIdx.x; i < C4DIM * TDIM; i += 256) {
            float v = p[i]; s += v; q = fmaf(v, v, q);
        }
    }
    ssum[threadIdx.x] = s; ssq[threadIdx.x] = q;
    __syncthreads();
    for (int off = 128; off > 0; off >>= 1) {
        if (threadIdx.x < off) {
            ssum[threadIdx.x] += ssum[threadIdx.x + off];
            ssq[threadIdx.x]  += ssq[threadIdx.x + off];
        }
        __syncthreads();
    }
    if (threadIdx.x == 0) {
        float m   = ssum[0] * (1.0f / 65536.0f);
        float var = ssq[0] * (1.0f / 65536.0f) - m * m;
        mu[b] = m; rstd[b] = rsqrtf(var + 1e-5f);
    }
}

// FEAT[m][j*512+i] (bf16) from X (2048x512, f32 or bf16); optional fused LayerNorm
template<bool LN, bool INBF>
__global__ void build_feat(const void* __restrict__ X, const float* __restrict__ stats,
                           const float* __restrict__ lnw, const float* __restrict__ lnb,
                           u16* __restrict__ FEAT) {
    int i = blockIdx.x * blockDim.x + threadIdx.x;   // 0..511
    int m = blockIdx.y;                              // 0..2047
    float v = INBF ? bf2f(((const u16*)X)[(size_t)m * TDIM + i])
                   : ((const float*)X)[(size_t)m * TDIM + i];
    if (LN) {
        int b = m >> 7, c = m & 127;
        v = (v - stats[b]) * stats[16 + b] * lnw[i * C4DIM + c] + lnb[i * C4DIM + c];
    }
    float f[NFEAT];
    features9(v, f);
    u16* out = FEAT + (size_t)m * (NFEAT * TDIM) + i;
#pragma unroll
    for (int j = 0; j < NFEAT; ++j) out[j * TDIM] = f2bf(f[j]);
}

// reduce 8 split-K partials (PART[z][m][64] f32) -> h1, then FEAT2[m][j*64+i] bf16
__global__ void build_feat2(const float* __restrict__ PART, u16* __restrict__ FEAT2) {
    int idx = blockIdx.x * blockDim.x + threadIdx.x;  // 2048*64
    int m = idx >> 6, i = idx & 63;
    float h = 0.f;
#pragma unroll
    for (int z = 0; z < 8; ++z) h += PART[((size_t)z * M_ROWS + m) * 64 + i];
    float f[NFEAT];
    features9(h, f);
    u16* out = FEAT2 + (size_t)m * (NFEAT * 64) + i;
#pragma unroll
    for (int j = 0; j < NFEAT; ++j) out[j * 64] = f2bf(f[j]);
}

// sum 4 split-K partials -> bf16
__global__ void reduce4_bf16(const float* __restrict__ P, u16* __restrict__ out) {
    int idx = (blockIdx.x * blockDim.x + threadIdx.x) * 4;   // over 2048*512
    const size_t PL = (size_t)M_ROWS * 512;
    float4 s = *reinterpret_cast<const float4*>(P + idx);
#pragma unroll
    for (int z = 1; z < 4; ++z) {
        float4 t = *reinterpret_cast<const float4*>(P + z * PL + idx);
        s.x += t.x; s.y += t.y; s.z += t.z; s.w += t.w;
    }
    ushort4 o; o.x = f2bf(s.x); o.y = f2bf(s.y); o.z = f2bf(s.z); o.w = f2bf(s.w);
    *reinterpret_cast<ushort4*>(out + idx) = o;
}

// out(f32) += sum of 4 split-K partials
__global__ void reduce4_add(const float* __restrict__ P, float* __restrict__ out) {
    int idx = (blockIdx.x * blockDim.x + threadIdx.x) * 4;
    const size_t PL = (size_t)M_ROWS * 512;
    float4 s = *reinterpret_cast<float4*>(out + idx);
#pragma unroll
    for (int z = 0; z < 4; ++z) {
        float4 t = *reinterpret_cast<const float4*>(P + z * PL + idx);
        s.x += t.x; s.y += t.y; s.z += t.z; s.w += t.w;
    }
    *reinterpret_cast<float4*>(out + idx) = s;
}

// ---------------------------------------------------------------------------
// bf16 MFMA NT GEMM:  C[m,n] = sum_k A[m][k]*B[n][k]
// 256 threads = 4 waves (2x2), BK=64, reg-staged LDS with +8 pad.
// EPI 0: f32 store to PART plane blockIdx.z
// EPI 1: bf16 store of acc + bf16 aux[m*N+n]          (residual)
// EPI 2: gelu(acc + f32 aux[n]) -> f32 or bf16 per OUTF32
// ---------------------------------------------------------------------------
template<int BM, int BN, int EPI, bool OUTF32>
__global__ __launch_bounds__(256)
void gemm_mfma(const u16* __restrict__ A, const u16* __restrict__ B,
               void* __restrict__ Cout, const void* __restrict__ aux,
               int M, int N, int Kd, int kPerZ) {
    constexpr int WSM = BM / 2, WSN = BN / 2;
    constexpr int FM = WSM / 16, FN = WSN / 16;
    constexpr int CA = BM / 32, CB = BN / 32;
    __shared__ u16 As[BM][72];
    __shared__ u16 Bs[BN][72];

    const int tid  = threadIdx.x;
    const int wave = tid >> 6, lane = tid & 63;
    const int wm = (wave >> 1) * WSM, wn = (wave & 1) * WSN;
    const int lr = lane & 15, kh = lane >> 4;
    const int bm = blockIdx.y * BM, bn = blockIdx.x * BN;
    const int k0 = blockIdx.z * kPerZ;

    const u16* Ab = A + (size_t)bm * Kd + k0;
    const u16* Bb = B + (size_t)bn * Kd + k0;

    f32x4 acc[FM][FN];
#pragma unroll
    for (int a = 0; a < FM; ++a)
#pragma unroll
        for (int b = 0; b < FN; ++b) acc[a][b] = (f32x4){0.f, 0.f, 0.f, 0.f};

    for (int kt = 0; kt < kPerZ; kt += 64) {
        uint4 ar[CA], br[CB];
#pragma unroll
        for (int c = 0; c < CA; ++c) {
            int id = tid + c * 256;
            ar[c] = *reinterpret_cast<const uint4*>(Ab + (size_t)(id >> 3) * Kd + kt + (id & 7) * 8);
        }
#pragma unroll
        for (int c = 0; c < CB; ++c) {
            int id = tid + c * 256;
            br[c] = *reinterpret_cast<const uint4*>(Bb + (size_t)(id >> 3) * Kd + kt + (id & 7) * 8);
        }
        __syncthreads();
#pragma unroll
        for (int c = 0; c < CA; ++c) {
            int id = tid + c * 256;
            *reinterpret_cast<uint4*>(&As[id >> 3][(id & 7) * 8]) = ar[c];
        }
#pragma unroll
        for (int c = 0; c < CB; ++c) {
            int id = tid + c * 256;
            *reinterpret_cast<uint4*>(&Bs[id >> 3][(id & 7) * 8]) = br[c];
        }
        __syncthreads();
#pragma unroll
        for (int ks = 0; ks < 2; ++ks) {
            short8 af[FM], bfr[FN];
#pragma unroll
            for (int a = 0; a < FM; ++a)
                af[a] = *reinterpret_cast<const short8*>(&As[wm + a * 16 + lr][ks * 32 + kh * 8]);
#pragma unroll
            for (int b = 0; b < FN; ++b)
                bfr[b] = *reinterpret_cast<const short8*>(&Bs[wn + b * 16 + lr][ks * 32 + kh * 8]);
#pragma unroll
            for (int a = 0; a < FM; ++a)
#pragma unroll
                for (int b = 0; b < FN; ++b)
                    acc[a][b] = __builtin_amdgcn_mfma_f32_16x16x32_bf16(af[a], bfr[b], acc[a][b], 0, 0, 0);
        }
    }

    // epilogue: D row = (lane>>4)*4 + reg, col = lane&15
    const int r0 = kh * 4;
#pragma unroll
    for (int a = 0; a < FM; ++a) {
#pragma unroll
        for (int b = 0; b < FN; ++b) {
#pragma unroll
            for (int r = 0; r < 4; ++r) {
                int row = bm + wm + a * 16 + r0 + r;
                int col = bn + wn + b * 16 + lr;
                float v = acc[a][b][r];
                if (EPI == 0) {
                    ((float*)Cout)[((size_t)blockIdx.z * M + row) * N + col] = v;
                } else if (EPI == 1) {
                    v += bf2f(((const u16*)aux)[(size_t)row * N + col]);
                    ((u16*)Cout)[(size_t)row * N + col] = f2bf(v);
                } else {  // EPI == 2
                    v = geluf(v + ((const float*)aux)[col]);
                    if (OUTF32) ((float*)Cout)[(size_t)row * N + col] = v;
                    else        ((u16*)Cout)[(size_t)row * N + col] = f2bf(v);
                }
            }
        }
    }
}

// ---------------------------------------------------------------------------
// launch
// ---------------------------------------------------------------------------
extern "C" void kernel_launch(void* const* d_in, const int* in_sizes, int n_in,
                              void* d_out, int out_size, void* d_ws, size_t ws_size,
                              hipStream_t stream) {
    const float* x            = (const float*)d_in[0];
    const float* tm1_ln_w     = (const float*)d_in[1];
    const float* tm1_ln_b     = (const float*)d_in[2];
    const float* tm1_k1_base  = (const float*)d_in[3];
    const float* tm1_k1_spl   = (const float*)d_in[4];
    const float* tm1_k2_base  = (const float*)d_in[5];
    const float* tm1_k2_spl   = (const float*)d_in[6];
    const float* g1_w         = (const float*)d_in[8];
    const float* g1_b         = (const float*)d_in[9];
    const float* k1_base      = (const float*)d_in[10];
    const float* k1_spl       = (const float*)d_in[11];
    const float* tm_ln_w      = (const float*)d_in[12];
    const float* tm_ln_b      = (const float*)d_in[13];
    const float* tm_k1_base   = (const float*)d_in[14];
    const float* tm_k1_spl    = (const float*)d_in[15];
    const float* tm_k2_base   = (const float*)d_in[16];
    const float* tm_k2_spl    = (const float*)d_in[17];
    const float* g2_w         = (const float*)d_in[19];
    const float* g2_b         = (const float*)d_in[20];
    const float* k2_base      = (const float*)d_in[21];
    const float* k2_spl       = (const float*)d_in[22];

    float* out = (float*)d_out;

    // ---- workspace layout -------------------------------------------------
    char* w = (char*)d_ws;
    u16*   FEAT  = (u16*)w;               w += (size_t)M_ROWS * 4608 * 2;   // 18.9 MB
    u16*   FEAT2 = (u16*)w;               w += (size_t)M_ROWS * 576 * 2;    // 2.4 MB
    float* PART  = (float*)w;             w += (size_t)4 * M_ROWS * 512 * 4;// 16.8 MB (also 8x2048x64)
    u16*   XB    = (u16*)w;               w += (size_t)M_ROWS * 512 * 2;
    u16*   BUF1  = (u16*)w;               w += (size_t)M_ROWS * 512 * 2;
    u16*   BUF2  = (u16*)w;               w += (size_t)M_ROWS * 512 * 2;
    u16*   BUF3  = (u16*)w;               w += (size_t)M_ROWS * 512 * 2;
    u16*   W1a   = (u16*)w;               w += (size_t)64 * 4608 * 2;
    u16*   W1b   = (u16*)w;               w += (size_t)64 * 4608 * 2;
    u16*   W2a   = (u16*)w;               w += (size_t)512 * 576 * 2;
    u16*   W2b   = (u16*)w;               w += (size_t)512 * 576 * 2;
    u16*   WE1   = (u16*)w;               w += (size_t)512 * 512 * 2;
    u16*   WE2   = (u16*)w;               w += (size_t)512 * 512 * 2;
    u16*   KX1   = (u16*)w;               w += (size_t)512 * 4608 * 2;      // 4.7 MB
    u16*   KX2   = (u16*)w;               w += (size_t)512 * 4608 * 2;
    float* STATS = (float*)w;

    // ---- weight preprocessing --------------------------------------------
    build_weff<<<1024, 256, 0, stream>>>(g1_w, WE1);
    build_weff<<<1024, 256, 0, stream>>>(g2_w, WE2);
    build_wcat<<<128,  256, 0, stream>>>(tm1_k1_base, tm1_k1_spl, W1a, 64, 512);
    build_wcat<<<128,  256, 0, stream>>>(tm_k1_base,  tm_k1_spl,  W1b, 64, 512);
    build_wcat<<<128,  256, 0, stream>>>(tm1_k2_base, tm1_k2_spl, W2a, 512, 64);
    build_wcat<<<128,  256, 0, stream>>>(tm_k2_base,  tm_k2_spl,  W2b, 512, 64);
    build_wcat<<<1024, 256, 0, stream>>>(k1_base, k1_spl, KX1, 512, 512);
    build_wcat<<<1024, 256, 0, stream>>>(k2_base, k2_spl, KX2, 512, 512);
    convert_f2bf<<<1024, 256, 0, stream>>>(x, XB);

    // ---- branch 1: tm1 = token_mixing(x); y1 = gelu(tm1 @ WE1 + b1) -> out
    stats_kernel<false><<<16, 256, 0, stream>>>(x, STATS, STATS + 16);
    build_feat<true, false><<<dim3(2, M_ROWS), 256, 0, stream>>>(x, STATS, tm1_ln_w, tm1_ln_b, FEAT);
    gemm_mfma<128, 64, 0, true><<<dim3(1, 16, 8), 256, 0, stream>>>(FEAT, W1a, PART, nullptr, M_ROWS, 64, 4608, 576);
    build_feat2<<<512, 256, 0, stream>>>(PART, FEAT2);
    gemm_mfma<64, 64, 1, false><<<dim3(8, 32, 1), 256, 0, stream>>>(FEAT2, W2a, BUF1, XB, M_ROWS, 512, 576, 576);
    gemm_mfma<64, 64, 2, true><<<dim3(8, 32, 1), 256, 0, stream>>>(BUF1, WE1, out, g1_b, M_ROWS, 512, 512, 512);

    // ---- branch 2: cm = kan(x); tm = token_mixing(cm); y2; z = kan(y2) ----
    build_feat<false, false><<<dim3(2, M_ROWS), 256, 0, stream>>>(x, nullptr, nullptr, nullptr, FEAT);
    gemm_mfma<128, 128, 0, true><<<dim3(4, 16, 4), 256, 0, stream>>>(FEAT, KX1, PART, nullptr, M_ROWS, 512, 4608, 1152);
    reduce4_bf16<<<1024, 256, 0, stream>>>(PART, BUF2);            // cm

    stats_kernel<true><<<16, 256, 0, stream>>>(BUF2, STATS + 32, STATS + 48);
    build_feat<true, true><<<dim3(2, M_ROWS), 256, 0, stream>>>(BUF2, STATS + 32, tm_ln_w, tm_ln_b, FEAT);
    gemm_mfma<128, 64, 0, true><<<dim3(1, 16, 8), 256, 0, stream>>>(FEAT, W1b, PART, nullptr, M_ROWS, 64, 4608, 576);
    build_feat2<<<512, 256, 0, stream>>>(PART, FEAT2);
    gemm_mfma<64, 64, 1, false><<<dim3(8, 32, 1), 256, 0, stream>>>(FEAT2, W2b, BUF1, BUF2, M_ROWS, 512, 576, 576);
    gemm_mfma<64, 64, 2, false><<<dim3(8, 32, 1), 256, 0, stream>>>(BUF1, WE2, BUF3, g2_b, M_ROWS, 512, 512, 512);

    build_feat<false, true><<<dim3(2, M_ROWS), 256, 0, stream>>>(BUF3, nullptr, nullptr, nullptr, FEAT);
    gemm_mfma<128, 128, 0, true><<<dim3(4, 16, 4), 256, 0, stream>>>(FEAT, KX2, PART, nullptr, M_ROWS, 512, 4608, 1152);
    reduce4_add<<<1024, 256, 0, stream>>>(PART, out);              // out = y1 + z
}

// Round 4
// 444.319 us; speedup vs baseline: 2.1199x; 1.2457x over previous
//
#include <hip/hip_runtime.h>
#include <hip/hip_bf16.h>

// Mixer2dTriUKAN forward — bf16 MFMA, fused stats, merged prep.
//
// Algebraic simplifications (verified):
//  * sum(softmax(P),-1) == 1  =>  prob_distance/FFT pipeline is dead code.
//  * concat([x,x,x]) @ g_w.T == x @ (sum of the three 512-col blocks).T

#define M_ROWS 2048
#define TDIM   512
#define C4DIM  128
#define NFEAT  9

typedef unsigned short u16;
typedef __attribute__((ext_vector_type(8))) short short8;
typedef __attribute__((ext_vector_type(4))) float f32x4;

// ---------------------------------------------------------------------------
// helpers
// ---------------------------------------------------------------------------
__device__ __forceinline__ float bf2f(u16 u) {
    union { unsigned int i; float f; } c; c.i = ((unsigned int)u) << 16; return c.f;
}
__device__ __forceinline__ u16 f2bf(float v) {
    __hip_bfloat16 h = __float2bfloat16(v);
    return *reinterpret_cast<u16*>(&h);
}
__device__ __forceinline__ float siluf(float v) { return v / (1.0f + __expf(-v)); }
__device__ __forceinline__ float geluf(float v) {
    return 0.5f * v * (1.0f + erff(v * 0.70710678118654752440f));
}

// silu + 8 cubic B-spline bases on uniform grid g[i] = (i-3)*0.4 - 1
__device__ __forceinline__ void features9(float v, float* f) {
    f[0] = siluf(v);
    float b[11];
#pragma unroll
    for (int i = 0; i < 11; ++i) {
        float gi  = (float)(i - 3) * 0.4f - 1.0f;
        float gi1 = (float)(i - 2) * 0.4f - 1.0f;
        b[i] = (v >= gi && v < gi1) ? 1.0f : 0.0f;
    }
#pragma unroll
    for (int k = 1; k <= 3; ++k) {
#pragma unroll
        for (int i = 0; i + k < 11; ++i) {
            float gi   = (float)(i - 3) * 0.4f - 1.0f;
            float gi1  = (float)(i - 2) * 0.4f - 1.0f;
            float gik  = (float)(i + k - 3) * 0.4f - 1.0f;
            float gik1 = (float)(i + k - 2) * 0.4f - 1.0f;
            b[i] = (v - gi) * (1.0f / (gik - gi)) * b[i]
                 + (gik1 - v) * (1.0f / (gik1 - gi1)) * b[i + 1];
        }
    }
#pragma unroll
    for (int k = 0; k < 8; ++k) f[1 + k] = b[k];
}

// ---------------------------------------------------------------------------
// merged weight-prep kernel (one launch; block-range dispatch)
// ---------------------------------------------------------------------------
struct PrepPtrs {
    const float *g1_w, *g2_w;
    const float *b1, *s1, *b2, *s2, *b3, *s3, *b4, *s4, *b5, *s5, *b6, *s6;
    u16 *WE1, *WE2, *W1a, *W1b, *W2a, *W2b, *KX1, *KX2;
    const float *ln1w, *ln1b, *ln2w, *ln2b;
    float *LNT;   // 4 * 65536 transposed LN params
    float *SR;    // 64 floats of stats accumulators (zeroed here)
};

__device__ __forceinline__ void wcat_one(const float* bw, const float* sw, u16* out,
                                         int idx, int I) {
    int o = idx / I, i = idx - o * I;
    u16* w = out + (size_t)o * NFEAT * I;
    w[i] = f2bf(bw[idx]);
    const float* sp = sw + (size_t)idx * 8;
#pragma unroll
    for (int k = 0; k < 8; ++k) w[(1 + k) * I + i] = f2bf(sp[k]);
}

__global__ void prep_all(PrepPtrs p) {
    int blk = blockIdx.x, tid = threadIdx.x;
    if (blk < 2048) {                                   // weff x2
        const float* gw = blk < 1024 ? p.g1_w : p.g2_w;
        u16* we = blk < 1024 ? p.WE1 : p.WE2;
        int idx = (blk & 1023) * 256 + tid;
        int o = idx >> 9, i = idx & 511;
        const float* r = gw + (size_t)o * 1536;
        we[idx] = f2bf(r[i] + r[512 + i] + r[1024 + i]);
    } else if (blk < 2560) {                            // 4 small wcat (32768 each)
        int sub = blk - 2048, which = sub >> 7;
        int idx = (sub & 127) * 256 + tid;
        if (which == 0)      wcat_one(p.b1, p.s1, p.W1a, idx, 512);
        else if (which == 1) wcat_one(p.b2, p.s2, p.W1b, idx, 512);
        else if (which == 2) wcat_one(p.b3, p.s3, p.W2a, idx, 64);
        else                 wcat_one(p.b4, p.s4, p.W2b, idx, 64);
    } else if (blk < 4608) {                            // 2 big wcat (262144 each)
        int sub = blk - 2560;
        int idx = (sub & 1023) * 256 + tid;
        if (sub < 1024) wcat_one(p.b5, p.s5, p.KX1, idx, 512);
        else            wcat_one(p.b6, p.s6, p.KX2, idx, 512);
    } else if (blk < 5632) {                            // LN transpose x4
        int sub = blk - 4608, which = sub >> 8;
        const float* src = which == 0 ? p.ln1w : which == 1 ? p.ln1b
                         : which == 2 ? p.ln2w : p.ln2b;
        float* dst = p.LNT + (size_t)which * 65536;
        int idx = (sub & 255) * 256 + tid;              // idx = l*128 + c
        int c = idx & 127, l = idx >> 7;
        dst[c * 512 + l] = src[idx];
    } else {                                            // zero stats accumulators
        if (tid < 64) p.SR[tid] = 0.f;
    }
}

// ---------------------------------------------------------------------------
// stats stage 1 (branch 1): reads x f32, writes bf16 copy, accumulates sums
// ---------------------------------------------------------------------------
__global__ void stats1_convert(const float* __restrict__ X, u16* __restrict__ XB,
                               float* __restrict__ SR) {
    int idx = (blockIdx.x * 256 + threadIdx.x) * 4;
    float4 v = *reinterpret_cast<const float4*>(X + idx);
    ushort4 o; o.x = f2bf(v.x); o.y = f2bf(v.y); o.z = f2bf(v.z); o.w = f2bf(v.w);
    *reinterpret_cast<ushort4*>(XB + idx) = o;
    float s = v.x + v.y + v.z + v.w;
    float q = v.x * v.x + v.y * v.y + v.z * v.z + v.w * v.w;
#pragma unroll
    for (int off = 32; off > 0; off >>= 1) {
        s += __shfl_down(s, off);
        q += __shfl_down(q, off);
    }
    __shared__ float ls[4], lq[4];
    int wv = threadIdx.x >> 6;
    if ((threadIdx.x & 63) == 0) { ls[wv] = s; lq[wv] = q; }
    __syncthreads();
    if (threadIdx.x == 0) {
        s = ls[0] + ls[1] + ls[2] + ls[3];
        q = lq[0] + lq[1] + lq[2] + lq[3];
        int b = (blockIdx.x * 1024) >> 16;   // 64 blocks per batch
        atomicAdd(&SR[b * 2], s);
        atomicAdd(&SR[b * 2 + 1], q);
    }
}

// sum 4 split-K partials -> bf16 cm, and accumulate cm stats (branch 2)
__global__ void reduce4_bf16_stats(const float* __restrict__ P, u16* __restrict__ out,
                                   float* __restrict__ SR) {
    int idx = (blockIdx.x * 256 + threadIdx.x) * 4;
    const size_t PL = (size_t)M_ROWS * 512;
    float4 sv = *reinterpret_cast<const float4*>(P + idx);
#pragma unroll
    for (int z = 1; z < 4; ++z) {
        float4 t = *reinterpret_cast<const float4*>(P + z * PL + idx);
        sv.x += t.x; sv.y += t.y; sv.z += t.z; sv.w += t.w;
    }
    ushort4 o; o.x = f2bf(sv.x); o.y = f2bf(sv.y); o.z = f2bf(sv.z); o.w = f2bf(sv.w);
    *reinterpret_cast<ushort4*>(out + idx) = o;
    float s = sv.x + sv.y + sv.z + sv.w;
    float q = sv.x * sv.x + sv.y * sv.y + sv.z * sv.z + sv.w * sv.w;
#pragma unroll
    for (int off = 32; off > 0; off >>= 1) {
        s += __shfl_down(s, off);
        q += __shfl_down(q, off);
    }
    __shared__ float ls[4], lq[4];
    int wv = threadIdx.x >> 6;
    if ((threadIdx.x & 63) == 0) { ls[wv] = s; lq[wv] = q; }
    __syncthreads();
    if (threadIdx.x == 0) {
        s = ls[0] + ls[1] + ls[2] + ls[3];
        q = lq[0] + lq[1] + lq[2] + lq[3];
        int b = (blockIdx.x * 1024) >> 16;
        atomicAdd(&SR[b * 2], s);
        atomicAdd(&SR[b * 2 + 1], q);
    }
}

// ---------------------------------------------------------------------------
// FEAT[m][j*512+i] (bf16); optional fused LayerNorm with inline mu/rstd
// ---------------------------------------------------------------------------
template<bool LN, bool INBF>
__global__ void build_feat(const void* __restrict__ X, const float* __restrict__ SR,
                           const float* __restrict__ lnwT, const float* __restrict__ lnbT,
                           u16* __restrict__ FEAT) {
    int i = blockIdx.x * blockDim.x + threadIdx.x;   // 0..511
    int m = blockIdx.y;                              // 0..2047
    float v = INBF ? bf2f(((const u16*)X)[(size_t)m * TDIM + i])
                   : ((const float*)X)[(size_t)m * TDIM + i];
    if (LN) {
        int b = m >> 7, c = m & 127;
        float mu   = SR[b * 2] * (1.0f / 65536.0f);
        float var  = SR[b * 2 + 1] * (1.0f / 65536.0f) - mu * mu;
        float rstd = rsqrtf(var + 1e-5f);
        v = (v - mu) * rstd * lnwT[c * 512 + i] + lnbT[c * 512 + i];
    }
    float f[NFEAT];
    features9(v, f);
    u16* out = FEAT + (size_t)m * (NFEAT * TDIM) + i;
#pragma unroll
    for (int j = 0; j < NFEAT; ++j) out[j * TDIM] = f2bf(f[j]);
}

// reduce 8 split-K partials (PART[z][m][64] f32) -> h1, then FEAT2[m][j*64+i] bf16
__global__ void build_feat2(const float* __restrict__ PART, u16* __restrict__ FEAT2) {
    int idx = blockIdx.x * blockDim.x + threadIdx.x;  // 2048*64
    int m = idx >> 6, i = idx & 63;
    float h = 0.f;
#pragma unroll
    for (int z = 0; z < 8; ++z) h += PART[((size_t)z * M_ROWS + m) * 64 + i];
    float f[NFEAT];
    features9(h, f);
    u16* out = FEAT2 + (size_t)m * (NFEAT * 64) + i;
#pragma unroll
    for (int j = 0; j < NFEAT; ++j) out[j * 64] = f2bf(f[j]);
}

// out(f32) += sum of 4 split-K partials
__global__ void reduce4_add(const float* __restrict__ P, float* __restrict__ out) {
    int idx = (blockIdx.x * 256 + threadIdx.x) * 4;
    const size_t PL = (size_t)M_ROWS * 512;
    float4 s = *reinterpret_cast<float4*>(out + idx);
#pragma unroll
    for (int z = 0; z < 4; ++z) {
        float4 t = *reinterpret_cast<const float4*>(P + z * PL + idx);
        s.x += t.x; s.y += t.y; s.z += t.z; s.w += t.w;
    }
    *reinterpret_cast<float4*>(out + idx) = s;
}

// ---------------------------------------------------------------------------
// bf16 MFMA NT GEMM:  C[m,n] = sum_k A[m][k]*B[n][k]
// 256 threads = 4 waves (2x2), BK=64, reg-staged LDS (+8 u16 pad).
// EPI 0: f32 store to plane blockIdx.z   EPI 1: bf16 acc + bf16 aux (residual)
// EPI 2: gelu(acc + f32 aux[n]) -> f32/bf16 per OUTF32
// ---------------------------------------------------------------------------
template<int BM, int BN, int EPI, bool OUTF32>
__global__ __launch_bounds__(256)
void gemm_mfma(const u16* __restrict__ A, const u16* __restrict__ B,
               void* __restrict__ Cout, const void* __restrict__ aux,
               int M, int N, int Kd, int kPerZ) {
    constexpr int WSM = BM / 2, WSN = BN / 2;
    constexpr int FM = WSM / 16, FN = WSN / 16;
    constexpr int CA = BM / 32, CB = BN / 32;
    __shared__ u16 As[BM][72];
    __shared__ u16 Bs[BN][72];

    const int tid  = threadIdx.x;
    const int wave = tid >> 6, lane = tid & 63;
    const int wm = (wave >> 1) * WSM, wn = (wave & 1) * WSN;
    const int lr = lane & 15, kh = lane >> 4;
    const int bm = blockIdx.y * BM, bn = blockIdx.x * BN;
    const int k0 = blockIdx.z * kPerZ;

    const u16* Ab = A + (size_t)bm * Kd + k0;
    const u16* Bb = B + (size_t)bn * Kd + k0;

    f32x4 acc[FM][FN];
#pragma unroll
    for (int a = 0; a < FM; ++a)
#pragma unroll
        for (int b = 0; b < FN; ++b) acc[a][b] = (f32x4){0.f, 0.f, 0.f, 0.f};

    for (int kt = 0; kt < kPerZ; kt += 64) {
        uint4 ar[CA], br[CB];
#pragma unroll
        for (int c = 0; c < CA; ++c) {
            int id = tid + c * 256;
            ar[c] = *reinterpret_cast<const uint4*>(Ab + (size_t)(id >> 3) * Kd + kt + (id & 7) * 8);
        }
#pragma unroll
        for (int c = 0; c < CB; ++c) {
            int id = tid + c * 256;
            br[c] = *reinterpret_cast<const uint4*>(Bb + (size_t)(id >> 3) * Kd + kt + (id & 7) * 8);
        }
        __syncthreads();
#pragma unroll
        for (int c = 0; c < CA; ++c) {
            int id = tid + c * 256;
            *reinterpret_cast<uint4*>(&As[id >> 3][(id & 7) * 8]) = ar[c];
        }
#pragma unroll
        for (int c = 0; c < CB; ++c) {
            int id = tid + c * 256;
            *reinterpret_cast<uint4*>(&Bs[id >> 3][(id & 7) * 8]) = br[c];
        }
        __syncthreads();
#pragma unroll
        for (int ks = 0; ks < 2; ++ks) {
            short8 af[FM], bfr[FN];
#pragma unroll
            for (int a = 0; a < FM; ++a)
                af[a] = *reinterpret_cast<const short8*>(&As[wm + a * 16 + lr][ks * 32 + kh * 8]);
#pragma unroll
            for (int b = 0; b < FN; ++b)
                bfr[b] = *reinterpret_cast<const short8*>(&Bs[wn + b * 16 + lr][ks * 32 + kh * 8]);
#pragma unroll
            for (int a = 0; a < FM; ++a)
#pragma unroll
                for (int b = 0; b < FN; ++b)
                    acc[a][b] = __builtin_amdgcn_mfma_f32_16x16x32_bf16(af[a], bfr[b], acc[a][b], 0, 0, 0);
        }
    }

    const int r0 = kh * 4;   // D: row=(lane>>4)*4+reg, col=lane&15
#pragma unroll
    for (int a = 0; a < FM; ++a) {
#pragma unroll
        for (int b = 0; b < FN; ++b) {
#pragma unroll
            for (int r = 0; r < 4; ++r) {
                int row = bm + wm + a * 16 + r0 + r;
                int col = bn + wn + b * 16 + lr;
                float v = acc[a][b][r];
                if (EPI == 0) {
                    ((float*)Cout)[((size_t)blockIdx.z * M + row) * N + col] = v;
                } else if (EPI == 1) {
                    v += bf2f(((const u16*)aux)[(size_t)row * N + col]);
                    ((u16*)Cout)[(size_t)row * N + col] = f2bf(v);
                } else {  // EPI == 2
                    v = geluf(v + ((const float*)aux)[col]);
                    if (OUTF32) ((float*)Cout)[(size_t)row * N + col] = v;
                    else        ((u16*)Cout)[(size_t)row * N + col] = f2bf(v);
                }
            }
        }
    }
}

// ---------------------------------------------------------------------------
// launch
// ---------------------------------------------------------------------------
extern "C" void kernel_launch(void* const* d_in, const int* in_sizes, int n_in,
                              void* d_out, int out_size, void* d_ws, size_t ws_size,
                              hipStream_t stream) {
    const float* x            = (const float*)d_in[0];
    const float* tm1_ln_w     = (const float*)d_in[1];
    const float* tm1_ln_b     = (const float*)d_in[2];
    const float* tm1_k1_base  = (const float*)d_in[3];
    const float* tm1_k1_spl   = (const float*)d_in[4];
    const float* tm1_k2_base  = (const float*)d_in[5];
    const float* tm1_k2_spl   = (const float*)d_in[6];
    const float* g1_w         = (const float*)d_in[8];
    const float* g1_b         = (const float*)d_in[9];
    const float* k1_base      = (const float*)d_in[10];
    const float* k1_spl       = (const float*)d_in[11];
    const float* tm_ln_w      = (const float*)d_in[12];
    const float* tm_ln_b      = (const float*)d_in[13];
    const float* tm_k1_base   = (const float*)d_in[14];
    const float* tm_k1_spl    = (const float*)d_in[15];
    const float* tm_k2_base   = (const float*)d_in[16];
    const float* tm_k2_spl    = (const float*)d_in[17];
    const float* g2_w         = (const float*)d_in[19];
    const float* g2_b         = (const float*)d_in[20];
    const float* k2_base      = (const float*)d_in[21];
    const float* k2_spl       = (const float*)d_in[22];

    float* out = (float*)d_out;

    // ---- workspace layout -------------------------------------------------
    char* w = (char*)d_ws;
    u16*   FEAT  = (u16*)w;   w += (size_t)M_ROWS * 4608 * 2;
    u16*   FEAT2 = (u16*)w;   w += (size_t)M_ROWS * 576 * 2;
    float* PART  = (float*)w; w += (size_t)4 * M_ROWS * 512 * 4;
    u16*   XB    = (u16*)w;   w += (size_t)M_ROWS * 512 * 2;
    u16*   BUF1  = (u16*)w;   w += (size_t)M_ROWS * 512 * 2;
    u16*   BUF2  = (u16*)w;   w += (size_t)M_ROWS * 512 * 2;
    u16*   BUF3  = (u16*)w;   w += (size_t)M_ROWS * 512 * 2;
    u16*   W1a   = (u16*)w;   w += (size_t)64 * 4608 * 2;
    u16*   W1b   = (u16*)w;   w += (size_t)64 * 4608 * 2;
    u16*   W2a   = (u16*)w;   w += (size_t)512 * 576 * 2;
    u16*   W2b   = (u16*)w;   w += (size_t)512 * 576 * 2;
    u16*   WE1   = (u16*)w;   w += (size_t)512 * 512 * 2;
    u16*   WE2   = (u16*)w;   w += (size_t)512 * 512 * 2;
    u16*   KX1   = (u16*)w;   w += (size_t)512 * 4608 * 2;
    u16*   KX2   = (u16*)w;   w += (size_t)512 * 4608 * 2;
    float* LNT   = (float*)w; w += (size_t)4 * 65536 * 4;
    float* SR    = (float*)w; w += 64 * 4;
    const float* LNT0w = LNT, *LNT0b = LNT + 65536;
    const float* LNT2w = LNT + 131072, *LNT2b = LNT + 196608;

    // ---- merged prep (weights, LN transpose, stats zeroing) ---------------
    PrepPtrs p;
    p.g1_w = g1_w; p.g2_w = g2_w;
    p.b1 = tm1_k1_base; p.s1 = tm1_k1_spl;
    p.b2 = tm_k1_base;  p.s2 = tm_k1_spl;
    p.b3 = tm1_k2_base; p.s3 = tm1_k2_spl;
    p.b4 = tm_k2_base;  p.s4 = tm_k2_spl;
    p.b5 = k1_base;     p.s5 = k1_spl;
    p.b6 = k2_base;     p.s6 = k2_spl;
    p.WE1 = WE1; p.WE2 = WE2; p.W1a = W1a; p.W1b = W1b;
    p.W2a = W2a; p.W2b = W2b; p.KX1 = KX1; p.KX2 = KX2;
    p.ln1w = tm1_ln_w; p.ln1b = tm1_ln_b; p.ln2w = tm_ln_w; p.ln2b = tm_ln_b;
    p.LNT = LNT; p.SR = SR;
    prep_all<<<5633, 256, 0, stream>>>(p);

    // ---- branch 1: tm1 = token_mixing(x); y1 = gelu(tm1 @ WE1 + b1) -> out
    stats1_convert<<<1024, 256, 0, stream>>>(x, XB, SR);
    build_feat<true, false><<<dim3(2, M_ROWS), 256, 0, stream>>>(x, SR, LNT0w, LNT0b, FEAT);
    gemm_mfma<64, 64, 0, true><<<dim3(1, 32, 8), 256, 0, stream>>>(FEAT, W1a, PART, nullptr, M_ROWS, 64, 4608, 576);
    build_feat2<<<512, 256, 0, stream>>>(PART, FEAT2);
    gemm_mfma<64, 64, 1, false><<<dim3(8, 32, 1), 256, 0, stream>>>(FEAT2, W2a, BUF1, XB, M_ROWS, 512, 576, 576);
    gemm_mfma<64, 64, 2, true><<<dim3(8, 32, 1), 256, 0, stream>>>(BUF1, WE1, out, g1_b, M_ROWS, 512, 512, 512);

    // ---- branch 2: cm = kan(x); tm = token_mixing(cm); y2; z = kan(y2) ----
    build_feat<false, false><<<dim3(2, M_ROWS), 256, 0, stream>>>(x, nullptr, nullptr, nullptr, FEAT);
    gemm_mfma<128, 128, 0, true><<<dim3(4, 16, 4), 256, 0, stream>>>(FEAT, KX1, PART, nullptr, M_ROWS, 512, 4608, 1152);
    reduce4_bf16_stats<<<1024, 256, 0, stream>>>(PART, BUF2, SR + 32);

    build_feat<true, true><<<dim3(2, M_ROWS), 256, 0, stream>>>(BUF2, SR + 32, LNT2w, LNT2b, FEAT);
    gemm_mfma<64, 64, 0, true><<<dim3(1, 32, 8), 256, 0, stream>>>(FEAT, W1b, PART, nullptr, M_ROWS, 64, 4608, 576);
    build_feat2<<<512, 256, 0, stream>>>(PART, FEAT2);
    gemm_mfma<64, 64, 1, false><<<dim3(8, 32, 1), 256, 0, stream>>>(FEAT2, W2b, BUF1, BUF2, M_ROWS, 512, 576, 576);
    gemm_mfma<64, 64, 2, false><<<dim3(8, 32, 1), 256, 0, stream>>>(BUF1, WE2, BUF3, g2_b, M_ROWS, 512, 512, 512);

    build_feat<false, true><<<dim3(2, M_ROWS), 256, 0, stream>>>(BUF3, nullptr, nullptr, nullptr, FEAT);
    gemm_mfma<128, 128, 0, true><<<dim3(4, 16, 4), 256, 0, stream>>>(FEAT, KX2, PART, nullptr, M_ROWS, 512, 4608, 1152);
    reduce4_add<<<1024, 256, 0, stream>>>(PART, out);
}

// Round 6
// 431.254 us; speedup vs baseline: 2.1841x; 1.0303x over previous
//
#include <hip/hip_runtime.h>
#include <hip/hip_bf16.h>

// Mixer2dTriUKAN forward — bf16 MFMA, prefetch-pipelined GEMMs, 512-block grids.
//
// Algebraic simplifications (verified):
//  * sum(softmax(P),-1) == 1  =>  prob_distance/FFT pipeline is dead code.
//  * concat([x,x,x]) @ g_w.T == x @ (sum of the three 512-col blocks).T

#define M_ROWS 2048
#define TDIM   512
#define C4DIM  128
#define NFEAT  9
#define HZ     12      // split-K planes for the N=64 hidden GEMMs

typedef unsigned short u16;
typedef __attribute__((ext_vector_type(8))) short short8;
typedef __attribute__((ext_vector_type(4))) float f32x4;

// ---------------------------------------------------------------------------
// helpers
// ---------------------------------------------------------------------------
__device__ __forceinline__ float bf2f(u16 u) {
    union { unsigned int i; float f; } c; c.i = ((unsigned int)u) << 16; return c.f;
}
__device__ __forceinline__ u16 f2bf(float v) {
    __hip_bfloat16 h = __float2bfloat16(v);
    return *reinterpret_cast<u16*>(&h);
}
__device__ __forceinline__ float siluf(float v) { return v / (1.0f + __expf(-v)); }
__device__ __forceinline__ float geluf(float v) {
    return 0.5f * v * (1.0f + erff(v * 0.70710678118654752440f));
}

// silu + 8 cubic B-spline bases on uniform grid g[i] = (i-3)*0.4 - 1
__device__ __forceinline__ void features9(float v, float* f) {
    f[0] = siluf(v);
    float b[11];
#pragma unroll
    for (int i = 0; i < 11; ++i) {
        float gi  = (float)(i - 3) * 0.4f - 1.0f;
        float gi1 = (float)(i - 2) * 0.4f - 1.0f;
        b[i] = (v >= gi && v < gi1) ? 1.0f : 0.0f;
    }
#pragma unroll
    for (int k = 1; k <= 3; ++k) {
#pragma unroll
        for (int i = 0; i + k < 11; ++i) {
            float gi   = (float)(i - 3) * 0.4f - 1.0f;
            float gi1  = (float)(i - 2) * 0.4f - 1.0f;
            float gik  = (float)(i + k - 3) * 0.4f - 1.0f;
            float gik1 = (float)(i + k - 2) * 0.4f - 1.0f;
            b[i] = (v - gi) * (1.0f / (gik - gi)) * b[i]
                 + (gik1 - v) * (1.0f / (gik1 - gi1)) * b[i + 1];
        }
    }
#pragma unroll
    for (int k = 0; k < 8; ++k) f[1 + k] = b[k];
}

// ---------------------------------------------------------------------------
// merged weight-prep kernel (one launch; block-range dispatch)
// ---------------------------------------------------------------------------
struct PrepPtrs {
    const float *g1_w, *g2_w;
    const float *b1, *s1, *b2, *s2, *b3, *s3, *b4, *s4, *b5, *s5, *b6, *s6;
    u16 *WE1, *WE2, *W1a, *W1b, *W2a, *W2b, *KX1, *KX2;
    const float *ln1w, *ln1b, *ln2w, *ln2b;
    float *LNT;   // 4 * 65536 transposed LN params
    float *SR;    // 64 floats of stats accumulators (zeroed here)
};

__device__ __forceinline__ void wcat_one(const float* bw, const float* sw, u16* out,
                                         int idx, int I) {
    int o = idx / I, i = idx - o * I;
    u16* w = out + (size_t)o * NFEAT * I;
    w[i] = f2bf(bw[idx]);
    const float* sp = sw + (size_t)idx * 8;
#pragma unroll
    for (int k = 0; k < 8; ++k) w[(1 + k) * I + i] = f2bf(sp[k]);
}

__global__ void prep_all(PrepPtrs p) {
    int blk = blockIdx.x, tid = threadIdx.x;
    if (blk < 2048) {                                   // weff x2
        const float* gw = blk < 1024 ? p.g1_w : p.g2_w;
        u16* we = blk < 1024 ? p.WE1 : p.WE2;
        int idx = (blk & 1023) * 256 + tid;
        int o = idx >> 9, i = idx & 511;
        const float* r = gw + (size_t)o * 1536;
        we[idx] = f2bf(r[i] + r[512 + i] + r[1024 + i]);
    } else if (blk < 2560) {                            // 4 small wcat (32768 each)
        int sub = blk - 2048, which = sub >> 7;
        int idx = (sub & 127) * 256 + tid;
        if (which == 0)      wcat_one(p.b1, p.s1, p.W1a, idx, 512);
        else if (which == 1) wcat_one(p.b2, p.s2, p.W1b, idx, 512);
        else if (which == 2) wcat_one(p.b3, p.s3, p.W2a, idx, 64);
        else                 wcat_one(p.b4, p.s4, p.W2b, idx, 64);
    } else if (blk < 4608) {                            // 2 big wcat (262144 each)
        int sub = blk - 2560;
        int idx = (sub & 1023) * 256 + tid;
        if (sub < 1024) wcat_one(p.b5, p.s5, p.KX1, idx, 512);
        else            wcat_one(p.b6, p.s6, p.KX2, idx, 512);
    } else if (blk < 5632) {                            // LN transpose x4
        int sub = blk - 4608, which = sub >> 8;
        const float* src = which == 0 ? p.ln1w : which == 1 ? p.ln1b
                         : which == 2 ? p.ln2w : p.ln2b;
        float* dst = p.LNT + (size_t)which * 65536;
        int idx = (sub & 255) * 256 + tid;              // idx = l*128 + c
        int c = idx & 127, l = idx >> 7;
        dst[c * 512 + l] = src[idx];
    } else {                                            // zero stats accumulators
        if (tid < 64) p.SR[tid] = 0.f;
    }
}

// ---------------------------------------------------------------------------
// stats stage 1 (branch 1): reads x f32, writes bf16 copy, accumulates sums
// ---------------------------------------------------------------------------
__global__ void stats1_convert(const float* __restrict__ X, u16* __restrict__ XB,
                               float* __restrict__ SR) {
    int idx = (blockIdx.x * 256 + threadIdx.x) * 4;
    float4 v = *reinterpret_cast<const float4*>(X + idx);
    ushort4 o; o.x = f2bf(v.x); o.y = f2bf(v.y); o.z = f2bf(v.z); o.w = f2bf(v.w);
    *reinterpret_cast<ushort4*>(XB + idx) = o;
    float s = v.x + v.y + v.z + v.w;
    float q = v.x * v.x + v.y * v.y + v.z * v.z + v.w * v.w;
#pragma unroll
    for (int off = 32; off > 0; off >>= 1) {
        s += __shfl_down(s, off);
        q += __shfl_down(q, off);
    }
    __shared__ float ls[4], lq[4];
    int wv = threadIdx.x >> 6;
    if ((threadIdx.x & 63) == 0) { ls[wv] = s; lq[wv] = q; }
    __syncthreads();
    if (threadIdx.x == 0) {
        s = ls[0] + ls[1] + ls[2] + ls[3];
        q = lq[0] + lq[1] + lq[2] + lq[3];
        int b = (blockIdx.x * 1024) >> 16;   // 64 blocks per batch
        atomicAdd(&SR[b * 2], s);
        atomicAdd(&SR[b * 2 + 1], q);
    }
}

// sum 4 split-K partials -> bf16 cm, and accumulate cm stats (branch 2)
__global__ void reduce4_bf16_stats(const float* __restrict__ P, u16* __restrict__ out,
                                   float* __restrict__ SR) {
    int idx = (blockIdx.x * 256 + threadIdx.x) * 4;
    const size_t PL = (size_t)M_ROWS * 512;
    float4 sv = *reinterpret_cast<const float4*>(P + idx);
#pragma unroll
    for (int z = 1; z < 4; ++z) {
        float4 t = *reinterpret_cast<const float4*>(P + z * PL + idx);
        sv.x += t.x; sv.y += t.y; sv.z += t.z; sv.w += t.w;
    }
    ushort4 o; o.x = f2bf(sv.x); o.y = f2bf(sv.y); o.z = f2bf(sv.z); o.w = f2bf(sv.w);
    *reinterpret_cast<ushort4*>(out + idx) = o;
    float s = sv.x + sv.y + sv.z + sv.w;
    float q = sv.x * sv.x + sv.y * sv.y + sv.z * sv.z + sv.w * sv.w;
#pragma unroll
    for (int off = 32; off > 0; off >>= 1) {
        s += __shfl_down(s, off);
        q += __shfl_down(q, off);
    }
    __shared__ float ls[4], lq[4];
    int wv = threadIdx.x >> 6;
    if ((threadIdx.x & 63) == 0) { ls[wv] = s; lq[wv] = q; }
    __syncthreads();
    if (threadIdx.x == 0) {
        s = ls[0] + ls[1] + ls[2] + ls[3];
        q = lq[0] + lq[1] + lq[2] + lq[3];
        int b = (blockIdx.x * 1024) >> 16;
        atomicAdd(&SR[b * 2], s);
        atomicAdd(&SR[b * 2 + 1], q);
    }
}

// ---------------------------------------------------------------------------
// FEAT[m][j*512+i] (bf16); optional fused LayerNorm with inline mu/rstd
// ---------------------------------------------------------------------------
template<bool LN, bool INBF>
__global__ void build_feat(const void* __restrict__ X, const float* __restrict__ SR,
                           const float* __restrict__ lnwT, const float* __restrict__ lnbT,
                           u16* __restrict__ FEAT) {
    int i = blockIdx.x * blockDim.x + threadIdx.x;   // 0..511
    int m = blockIdx.y;                              // 0..2047
    float v = INBF ? bf2f(((const u16*)X)[(size_t)m * TDIM + i])
                   : ((const float*)X)[(size_t)m * TDIM + i];
    if (LN) {
        int b = m >> 7, c = m & 127;
        float mu   = SR[b * 2] * (1.0f / 65536.0f);
        float var  = SR[b * 2 + 1] * (1.0f / 65536.0f) - mu * mu;
        float rstd = rsqrtf(var + 1e-5f);
        v = (v - mu) * rstd * lnwT[c * 512 + i] + lnbT[c * 512 + i];
    }
    float f[NFEAT];
    features9(v, f);
    u16* out = FEAT + (size_t)m * (NFEAT * TDIM) + i;
#pragma unroll
    for (int j = 0; j < NFEAT; ++j) out[j * TDIM] = f2bf(f[j]);
}

// reduce HZ split-K partials (PART[z][m][64] f32) -> h1, then FEAT2[m][j*64+i] bf16
__global__ void build_feat2(const float* __restrict__ PART, u16* __restrict__ FEAT2) {
    int idx = blockIdx.x * blockDim.x + threadIdx.x;  // 2048*64
    int m = idx >> 6, i = idx & 63;
    float h = 0.f;
#pragma unroll
    for (int z = 0; z < HZ; ++z) h += PART[((size_t)z * M_ROWS + m) * 64 + i];
    float f[NFEAT];
    features9(h, f);
    u16* out = FEAT2 + (size_t)m * (NFEAT * 64) + i;
#pragma unroll
    for (int j = 0; j < NFEAT; ++j) out[j * 64] = f2bf(f[j]);
}

// out(f32) += sum of 4 split-K partials
__global__ void reduce4_add(const float* __restrict__ P, float* __restrict__ out) {
    int idx = (blockIdx.x * 256 + threadIdx.x) * 4;
    const size_t PL = (size_t)M_ROWS * 512;
    float4 s = *reinterpret_cast<float4*>(out + idx);
#pragma unroll
    for (int z = 0; z < 4; ++z) {
        float4 t = *reinterpret_cast<const float4*>(P + z * PL + idx);
        s.x += t.x; s.y += t.y; s.z += t.z; s.w += t.w;
    }
    *reinterpret_cast<float4*>(out + idx) = s;
}

// ---------------------------------------------------------------------------
// bf16 MFMA NT GEMM:  C[m,n] = sum_k A[m][k]*B[n][k]
// 256 threads = 4 waves (2x2), BK=64, reg-staged LDS (+8 u16 pad).
// Prefetch pipeline: next K-tile's global loads are issued BEFORE the MFMA
// block, so HBM latency overlaps compute (the following barrier drains them).
// EPI 0: f32 store to plane blockIdx.z   EPI 1: bf16 acc + bf16 aux (residual)
// EPI 2: gelu(acc + f32 aux[n]) -> f32/bf16 per OUTF32
// ---------------------------------------------------------------------------
template<int BM, int BN, int EPI, bool OUTF32>
__global__ __launch_bounds__(256)
void gemm_mfma(const u16* __restrict__ A, const u16* __restrict__ B,
               void* __restrict__ Cout, const void* __restrict__ aux,
               int M, int N, int Kd, int kPerZ) {
    constexpr int WSM = BM / 2, WSN = BN / 2;
    constexpr int FM = WSM / 16, FN = WSN / 16;
    constexpr int CA = BM / 32, CB = BN / 32;
    __shared__ u16 As[BM][72];
    __shared__ u16 Bs[BN][72];

    const int tid  = threadIdx.x;
    const int wave = tid >> 6, lane = tid & 63;
    const int wm = (wave >> 1) * WSM, wn = (wave & 1) * WSN;
    const int lr = lane & 15, kh = lane >> 4;
    const int bm = blockIdx.y * BM, bn = blockIdx.x * BN;
    const int k0 = blockIdx.z * kPerZ;

    const u16* Ab = A + (size_t)bm * Kd + k0;
    const u16* Bb = B + (size_t)bn * Kd + k0;

    f32x4 acc[FM][FN];
#pragma unroll
    for (int a = 0; a < FM; ++a)
#pragma unroll
        for (int b = 0; b < FN; ++b) acc[a][b] = (f32x4){0.f, 0.f, 0.f, 0.f};

    uint4 ar[CA], br[CB];
    // prologue: load first K-tile
#pragma unroll
    for (int c = 0; c < CA; ++c) {
        int id = tid + c * 256;
        ar[c] = *reinterpret_cast<const uint4*>(Ab + (size_t)(id >> 3) * Kd + (id & 7) * 8);
    }
#pragma unroll
    for (int c = 0; c < CB; ++c) {
        int id = tid + c * 256;
        br[c] = *reinterpret_cast<const uint4*>(Bb + (size_t)(id >> 3) * Kd + (id & 7) * 8);
    }

    for (int kt = 0; kt < kPerZ; kt += 64) {
        __syncthreads();     // previous iteration's MFMA reads are done
#pragma unroll
        for (int c = 0; c < CA; ++c) {
            int id = tid + c * 256;
            *reinterpret_cast<uint4*>(&As[id >> 3][(id & 7) * 8]) = ar[c];
        }
#pragma unroll
        for (int c = 0; c < CB; ++c) {
            int id = tid + c * 256;
            *reinterpret_cast<uint4*>(&Bs[id >> 3][(id & 7) * 8]) = br[c];
        }
        __syncthreads();     // LDS tile visible

        // prefetch next K-tile (overlaps with the MFMA block below)
        if (kt + 64 < kPerZ) {
#pragma unroll
            for (int c = 0; c < CA; ++c) {
                int id = tid + c * 256;
                ar[c] = *reinterpret_cast<const uint4*>(Ab + (size_t)(id >> 3) * Kd + kt + 64 + (id & 7) * 8);
            }
#pragma unroll
            for (int c = 0; c < CB; ++c) {
                int id = tid + c * 256;
                br[c] = *reinterpret_cast<const uint4*>(Bb + (size_t)(id >> 3) * Kd + kt + 64 + (id & 7) * 8);
            }
        }

#pragma unroll
        for (int ks = 0; ks < 2; ++ks) {
            short8 af[FM], bfr[FN];
#pragma unroll
            for (int a = 0; a < FM; ++a)
                af[a] = *reinterpret_cast<const short8*>(&As[wm + a * 16 + lr][ks * 32 + kh * 8]);
#pragma unroll
            for (int b = 0; b < FN; ++b)
                bfr[b] = *reinterpret_cast<const short8*>(&Bs[wn + b * 16 + lr][ks * 32 + kh * 8]);
#pragma unroll
            for (int a = 0; a < FM; ++a)
#pragma unroll
                for (int b = 0; b < FN; ++b)
                    acc[a][b] = __builtin_amdgcn_mfma_f32_16x16x32_bf16(af[a], bfr[b], acc[a][b], 0, 0, 0);
        }
    }

    const int r0 = kh * 4;   // D: row=(lane>>4)*4+reg, col=lane&15
#pragma unroll
    for (int a = 0; a < FM; ++a) {
#pragma unroll
        for (int b = 0; b < FN; ++b) {
#pragma unroll
            for (int r = 0; r < 4; ++r) {
                int row = bm + wm + a * 16 + r0 + r;
                int col = bn + wn + b * 16 + lr;
                float v = acc[a][b][r];
                if (EPI == 0) {
                    ((float*)Cout)[((size_t)blockIdx.z * M + row) * N + col] = v;
                } else if (EPI == 1) {
                    v += bf2f(((const u16*)aux)[(size_t)row * N + col]);
                    ((u16*)Cout)[(size_t)row * N + col] = f2bf(v);
                } else {  // EPI == 2
                    v = geluf(v + ((const float*)aux)[col]);
                    if (OUTF32) ((float*)Cout)[(size_t)row * N + col] = v;
                    else        ((u16*)Cout)[(size_t)row * N + col] = f2bf(v);
                }
            }
        }
    }
}

// ---------------------------------------------------------------------------
// launch
// ---------------------------------------------------------------------------
extern "C" void kernel_launch(void* const* d_in, const int* in_sizes, int n_in,
                              void* d_out, int out_size, void* d_ws, size_t ws_size,
                              hipStream_t stream) {
    const float* x            = (const float*)d_in[0];
    const float* tm1_ln_w     = (const float*)d_in[1];
    const float* tm1_ln_b     = (const float*)d_in[2];
    const float* tm1_k1_base  = (const float*)d_in[3];
    const float* tm1_k1_spl   = (const float*)d_in[4];
    const float* tm1_k2_base  = (const float*)d_in[5];
    const float* tm1_k2_spl   = (const float*)d_in[6];
    const float* g1_w         = (const float*)d_in[8];
    const float* g1_b         = (const float*)d_in[9];
    const float* k1_base      = (const float*)d_in[10];
    const float* k1_spl       = (const float*)d_in[11];
    const float* tm_ln_w      = (const float*)d_in[12];
    const float* tm_ln_b      = (const float*)d_in[13];
    const float* tm_k1_base   = (const float*)d_in[14];
    const float* tm_k1_spl    = (const float*)d_in[15];
    const float* tm_k2_base   = (const float*)d_in[16];
    const float* tm_k2_spl    = (const float*)d_in[17];
    const float* g2_w         = (const float*)d_in[19];
    const float* g2_b         = (const float*)d_in[20];
    const float* k2_base      = (const float*)d_in[21];
    const float* k2_spl       = (const float*)d_in[22];

    float* out = (float*)d_out;

    // ---- workspace layout -------------------------------------------------
    char* w = (char*)d_ws;
    u16*   FEAT  = (u16*)w;   w += (size_t)M_ROWS * 4608 * 2;
    u16*   FEAT2 = (u16*)w;   w += (size_t)M_ROWS * 576 * 2;
    float* PART  = (float*)w; w += (size_t)4 * M_ROWS * 512 * 4;   // also HZ x 2048 x 64
    u16*   XB    = (u16*)w;   w += (size_t)M_ROWS * 512 * 2;
    u16*   BUF1  = (u16*)w;   w += (size_t)M_ROWS * 512 * 2;
    u16*   BUF2  = (u16*)w;   w += (size_t)M_ROWS * 512 * 2;
    u16*   BUF3  = (u16*)w;   w += (size_t)M_ROWS * 512 * 2;
    u16*   W1a   = (u16*)w;   w += (size_t)64 * 4608 * 2;
    u16*   W1b   = (u16*)w;   w += (size_t)64 * 4608 * 2;
    u16*   W2a   = (u16*)w;   w += (size_t)512 * 576 * 2;
    u16*   W2b   = (u16*)w;   w += (size_t)512 * 576 * 2;
    u16*   WE1   = (u16*)w;   w += (size_t)512 * 512 * 2;
    u16*   WE2   = (u16*)w;   w += (size_t)512 * 512 * 2;
    u16*   KX1   = (u16*)w;   w += (size_t)512 * 4608 * 2;
    u16*   KX2   = (u16*)w;   w += (size_t)512 * 4608 * 2;
    float* LNT   = (float*)w; w += (size_t)4 * 65536 * 4;
    float* SR    = (float*)w; w += 64 * 4;
    const float* LNT0w = LNT, *LNT0b = LNT + 65536;
    const float* LNT2w = LNT + 131072, *LNT2b = LNT + 196608;

    // ---- merged prep (weights, LN transpose, stats zeroing) ---------------
    PrepPtrs p;
    p.g1_w = g1_w; p.g2_w = g2_w;
    p.b1 = tm1_k1_base; p.s1 = tm1_k1_spl;
    p.b2 = tm_k1_base;  p.s2 = tm_k1_spl;
    p.b3 = tm1_k2_base; p.s3 = tm1_k2_spl;
    p.b4 = tm_k2_base;  p.s4 = tm_k2_spl;
    p.b5 = k1_base;     p.s5 = k1_spl;
    p.b6 = k2_base;     p.s6 = k2_spl;
    p.WE1 = WE1; p.WE2 = WE2; p.W1a = W1a; p.W1b = W1b;
    p.W2a = W2a; p.W2b = W2b; p.KX1 = KX1; p.KX2 = KX2;
    p.ln1w = tm1_ln_w; p.ln1b = tm1_ln_b; p.ln2w = tm_ln_w; p.ln2b = tm_ln_b;
    p.LNT = LNT; p.SR = SR;
    prep_all<<<5633, 256, 0, stream>>>(p);

    // ---- branch 1: tm1 = token_mixing(x); y1 = gelu(tm1 @ WE1 + b1) -> out
    stats1_convert<<<1024, 256, 0, stream>>>(x, XB, SR);
    build_feat<true, false><<<dim3(2, M_ROWS), 256, 0, stream>>>(x, SR, LNT0w, LNT0b, FEAT);
    gemm_mfma<64, 64, 0, true><<<dim3(1, 32, HZ), 256, 0, stream>>>(FEAT, W1a, PART, nullptr, M_ROWS, 64, 4608, 4608 / HZ);
    build_feat2<<<512, 256, 0, stream>>>(PART, FEAT2);
    gemm_mfma<64, 32, 1, false><<<dim3(16, 32, 1), 256, 0, stream>>>(FEAT2, W2a, BUF1, XB, M_ROWS, 512, 576, 576);
    gemm_mfma<64, 32, 2, true><<<dim3(16, 32, 1), 256, 0, stream>>>(BUF1, WE1, out, g1_b, M_ROWS, 512, 512, 512);

    // ---- branch 2: cm = kan(x); tm = token_mixing(cm); y2; z = kan(y2) ----
    build_feat<false, false><<<dim3(2, M_ROWS), 256, 0, stream>>>(x, nullptr, nullptr, nullptr, FEAT);
    gemm_mfma<128, 64, 0, true><<<dim3(8, 16, 4), 256, 0, stream>>>(FEAT, KX1, PART, nullptr, M_ROWS, 512, 4608, 1152);
    reduce4_bf16_stats<<<1024, 256, 0, stream>>>(PART, BUF2, SR + 32);

    build_feat<true, true><<<dim3(2, M_ROWS), 256, 0, stream>>>(BUF2, SR + 32, LNT2w, LNT2b, FEAT);
    gemm_mfma<64, 64, 0, true><<<dim3(1, 32, HZ), 256, 0, stream>>>(FEAT, W1b, PART, nullptr, M_ROWS, 64, 4608, 4608 / HZ);
    build_feat2<<<512, 256, 0, stream>>>(PART, FEAT2);
    gemm_mfma<64, 32, 1, false><<<dim3(16, 32, 1), 256, 0, stream>>>(FEAT2, W2b, BUF1, BUF2, M_ROWS, 512, 576, 576);
    gemm_mfma<64, 32, 2, false><<<dim3(16, 32, 1), 256, 0, stream>>>(BUF1, WE2, BUF3, g2_b, M_ROWS, 512, 512, 512);

    build_feat<false, true><<<dim3(2, M_ROWS), 256, 0, stream>>>(BUF3, nullptr, nullptr, nullptr, FEAT);
    gemm_mfma<128, 64, 0, true><<<dim3(8, 16, 4), 256, 0, stream>>>(FEAT, KX2, PART, nullptr, M_ROWS, 512, 4608, 1152);
    reduce4_add<<<1024, 256, 0, stream>>>(PART, out);
}

// Round 7
// 396.662 us; speedup vs baseline: 2.3746x; 1.0872x over previous
//
#include <hip/hip_runtime.h>
#include <hip/hip_bf16.h>

// Mixer2dTriUKAN forward — bf16 MFMA; big GEMMs use XCD-swizzled 128x128 tiles.
//
// Algebraic simplifications (verified):
//  * sum(softmax(P),-1) == 1  =>  prob_distance/FFT pipeline is dead code.
//  * concat([x,x,x]) @ g_w.T == x @ (sum of the three 512-col blocks).T

#define M_ROWS 2048
#define TDIM   512
#define C4DIM  128
#define NFEAT  9
#define HZ     12      // split-K planes for the N=64 hidden GEMMs

typedef unsigned short u16;
typedef __attribute__((ext_vector_type(8))) short short8;
typedef __attribute__((ext_vector_type(4))) float f32x4;

// ---------------------------------------------------------------------------
// helpers
// ---------------------------------------------------------------------------
__device__ __forceinline__ float bf2f(u16 u) {
    union { unsigned int i; float f; } c; c.i = ((unsigned int)u) << 16; return c.f;
}
__device__ __forceinline__ u16 f2bf(float v) {
    __hip_bfloat16 h = __float2bfloat16(v);
    return *reinterpret_cast<u16*>(&h);
}
__device__ __forceinline__ float siluf(float v) { return v / (1.0f + __expf(-v)); }
__device__ __forceinline__ float geluf(float v) {
    return 0.5f * v * (1.0f + erff(v * 0.70710678118654752440f));
}

// silu + 8 cubic B-spline bases on uniform grid g[i] = (i-3)*0.4 - 1
__device__ __forceinline__ void features9(float v, float* f) {
    f[0] = siluf(v);
    float b[11];
#pragma unroll
    for (int i = 0; i < 11; ++i) {
        float gi  = (float)(i - 3) * 0.4f - 1.0f;
        float gi1 = (float)(i - 2) * 0.4f - 1.0f;
        b[i] = (v >= gi && v < gi1) ? 1.0f : 0.0f;
    }
#pragma unroll
    for (int k = 1; k <= 3; ++k) {
#pragma unroll
        for (int i = 0; i + k < 11; ++i) {
            float gi   = (float)(i - 3) * 0.4f - 1.0f;
            float gi1  = (float)(i - 2) * 0.4f - 1.0f;
            float gik  = (float)(i + k - 3) * 0.4f - 1.0f;
            float gik1 = (float)(i + k - 2) * 0.4f - 1.0f;
            b[i] = (v - gi) * (1.0f / (gik - gi)) * b[i]
                 + (gik1 - v) * (1.0f / (gik1 - gi1)) * b[i + 1];
        }
    }
#pragma unroll
    for (int k = 0; k < 8; ++k) f[1 + k] = b[k];
}

// ---------------------------------------------------------------------------
// merged weight-prep kernel (one launch; block-range dispatch)
// ---------------------------------------------------------------------------
struct PrepPtrs {
    const float *g1_w, *g2_w;
    const float *b1, *s1, *b2, *s2, *b3, *s3, *b4, *s4, *b5, *s5, *b6, *s6;
    u16 *WE1, *WE2, *W1a, *W1b, *W2a, *W2b, *KX1, *KX2;
    const float *ln1w, *ln1b, *ln2w, *ln2b;
    float *LNT;   // 4 * 65536 transposed LN params
    float *SR;    // 64 floats of stats accumulators (zeroed here)
};

__device__ __forceinline__ void wcat_one(const float* bw, const float* sw, u16* out,
                                         int idx, int I) {
    int o = idx / I, i = idx - o * I;
    u16* w = out + (size_t)o * NFEAT * I;
    w[i] = f2bf(bw[idx]);
    const float* sp = sw + (size_t)idx * 8;
#pragma unroll
    for (int k = 0; k < 8; ++k) w[(1 + k) * I + i] = f2bf(sp[k]);
}

__global__ void prep_all(PrepPtrs p) {
    int blk = blockIdx.x, tid = threadIdx.x;
    if (blk < 2048) {                                   // weff x2
        const float* gw = blk < 1024 ? p.g1_w : p.g2_w;
        u16* we = blk < 1024 ? p.WE1 : p.WE2;
        int idx = (blk & 1023) * 256 + tid;
        int o = idx >> 9, i = idx & 511;
        const float* r = gw + (size_t)o * 1536;
        we[idx] = f2bf(r[i] + r[512 + i] + r[1024 + i]);
    } else if (blk < 2560) {                            // 4 small wcat (32768 each)
        int sub = blk - 2048, which = sub >> 7;
        int idx = (sub & 127) * 256 + tid;
        if (which == 0)      wcat_one(p.b1, p.s1, p.W1a, idx, 512);
        else if (which == 1) wcat_one(p.b2, p.s2, p.W1b, idx, 512);
        else if (which == 2) wcat_one(p.b3, p.s3, p.W2a, idx, 64);
        else                 wcat_one(p.b4, p.s4, p.W2b, idx, 64);
    } else if (blk < 4608) {                            // 2 big wcat (262144 each)
        int sub = blk - 2560;
        int idx = (sub & 1023) * 256 + tid;
        if (sub < 1024) wcat_one(p.b5, p.s5, p.KX1, idx, 512);
        else            wcat_one(p.b6, p.s6, p.KX2, idx, 512);
    } else if (blk < 5632) {                            // LN transpose x4
        int sub = blk - 4608, which = sub >> 8;
        const float* src = which == 0 ? p.ln1w : which == 1 ? p.ln1b
                         : which == 2 ? p.ln2w : p.ln2b;
        float* dst = p.LNT + (size_t)which * 65536;
        int idx = (sub & 255) * 256 + tid;              // idx = l*128 + c
        int c = idx & 127, l = idx >> 7;
        dst[c * 512 + l] = src[idx];
    } else {                                            // zero stats accumulators
        if (tid < 64) p.SR[tid] = 0.f;
    }
}

// ---------------------------------------------------------------------------
// stats stage 1 (branch 1): reads x f32, writes bf16 copy, accumulates sums
// ---------------------------------------------------------------------------
__global__ void stats1_convert(const float* __restrict__ X, u16* __restrict__ XB,
                               float* __restrict__ SR) {
    int idx = (blockIdx.x * 256 + threadIdx.x) * 4;
    float4 v = *reinterpret_cast<const float4*>(X + idx);
    ushort4 o; o.x = f2bf(v.x); o.y = f2bf(v.y); o.z = f2bf(v.z); o.w = f2bf(v.w);
    *reinterpret_cast<ushort4*>(XB + idx) = o;
    float s = v.x + v.y + v.z + v.w;
    float q = v.x * v.x + v.y * v.y + v.z * v.z + v.w * v.w;
#pragma unroll
    for (int off = 32; off > 0; off >>= 1) {
        s += __shfl_down(s, off);
        q += __shfl_down(q, off);
    }
    __shared__ float ls[4], lq[4];
    int wv = threadIdx.x >> 6;
    if ((threadIdx.x & 63) == 0) { ls[wv] = s; lq[wv] = q; }
    __syncthreads();
    if (threadIdx.x == 0) {
        s = ls[0] + ls[1] + ls[2] + ls[3];
        q = lq[0] + lq[1] + lq[2] + lq[3];
        int b = (blockIdx.x * 1024) >> 16;   // 64 blocks per batch
        atomicAdd(&SR[b * 2], s);
        atomicAdd(&SR[b * 2 + 1], q);
    }
}

// sum 4 split-K partials -> bf16 cm, and accumulate cm stats (branch 2)
__global__ void reduce4_bf16_stats(const float* __restrict__ P, u16* __restrict__ out,
                                   float* __restrict__ SR) {
    int idx = (blockIdx.x * 256 + threadIdx.x) * 4;
    const size_t PL = (size_t)M_ROWS * 512;
    float4 sv = *reinterpret_cast<const float4*>(P + idx);
#pragma unroll
    for (int z = 1; z < 4; ++z) {
        float4 t = *reinterpret_cast<const float4*>(P + z * PL + idx);
        sv.x += t.x; sv.y += t.y; sv.z += t.z; sv.w += t.w;
    }
    ushort4 o; o.x = f2bf(sv.x); o.y = f2bf(sv.y); o.z = f2bf(sv.z); o.w = f2bf(sv.w);
    *reinterpret_cast<ushort4*>(out + idx) = o;
    float s = sv.x + sv.y + sv.z + sv.w;
    float q = sv.x * sv.x + sv.y * sv.y + sv.z * sv.z + sv.w * sv.w;
#pragma unroll
    for (int off = 32; off > 0; off >>= 1) {
        s += __shfl_down(s, off);
        q += __shfl_down(q, off);
    }
    __shared__ float ls[4], lq[4];
    int wv = threadIdx.x >> 6;
    if ((threadIdx.x & 63) == 0) { ls[wv] = s; lq[wv] = q; }
    __syncthreads();
    if (threadIdx.x == 0) {
        s = ls[0] + ls[1] + ls[2] + ls[3];
        q = lq[0] + lq[1] + lq[2] + lq[3];
        int b = (blockIdx.x * 1024) >> 16;
        atomicAdd(&SR[b * 2], s);
        atomicAdd(&SR[b * 2 + 1], q);
    }
}

// ---------------------------------------------------------------------------
// FEAT[m][j*512+i] (bf16); optional fused LayerNorm with inline mu/rstd
// ---------------------------------------------------------------------------
template<bool LN, bool INBF>
__global__ void build_feat(const void* __restrict__ X, const float* __restrict__ SR,
                           const float* __restrict__ lnwT, const float* __restrict__ lnbT,
                           u16* __restrict__ FEAT) {
    int i = blockIdx.x * blockDim.x + threadIdx.x;   // 0..511
    int m = blockIdx.y;                              // 0..2047
    float v = INBF ? bf2f(((const u16*)X)[(size_t)m * TDIM + i])
                   : ((const float*)X)[(size_t)m * TDIM + i];
    if (LN) {
        int b = m >> 7, c = m & 127;
        float mu   = SR[b * 2] * (1.0f / 65536.0f);
        float var  = SR[b * 2 + 1] * (1.0f / 65536.0f) - mu * mu;
        float rstd = rsqrtf(var + 1e-5f);
        v = (v - mu) * rstd * lnwT[c * 512 + i] + lnbT[c * 512 + i];
    }
    float f[NFEAT];
    features9(v, f);
    u16* out = FEAT + (size_t)m * (NFEAT * TDIM) + i;
#pragma unroll
    for (int j = 0; j < NFEAT; ++j) out[j * TDIM] = f2bf(f[j]);
}

// reduce HZ split-K partials (PART[z][m][64] f32) -> h1, then FEAT2[m][j*64+i] bf16
__global__ void build_feat2(const float* __restrict__ PART, u16* __restrict__ FEAT2) {
    int idx = blockIdx.x * blockDim.x + threadIdx.x;  // 2048*64
    int m = idx >> 6, i = idx & 63;
    float h = 0.f;
#pragma unroll
    for (int z = 0; z < HZ; ++z) h += PART[((size_t)z * M_ROWS + m) * 64 + i];
    float f[NFEAT];
    features9(h, f);
    u16* out = FEAT2 + (size_t)m * (NFEAT * 64) + i;
#pragma unroll
    for (int j = 0; j < NFEAT; ++j) out[j * 64] = f2bf(f[j]);
}

// out(f32) += sum of 4 split-K partials
__global__ void reduce4_add(const float* __restrict__ P, float* __restrict__ out) {
    int idx = (blockIdx.x * 256 + threadIdx.x) * 4;
    const size_t PL = (size_t)M_ROWS * 512;
    float4 s = *reinterpret_cast<float4*>(out + idx);
#pragma unroll
    for (int z = 0; z < 4; ++z) {
        float4 t = *reinterpret_cast<const float4*>(P + z * PL + idx);
        s.x += t.x; s.y += t.y; s.z += t.z; s.w += t.w;
    }
    *reinterpret_cast<float4*>(out + idx) = s;
}

// ---------------------------------------------------------------------------
// BIG GEMM (M=2048, N=512, Kd=4608): 128x128 tile, 512 thr (8 waves, 2m x 4n),
// split-K z=4 (kPerZ=1152), grid = 256 blocks 1D with XCD-aware swizzle.
// XCD g gets blocks {lin % 8 == g} -> sw = g*32..g*32+31 = all 4 bn x 8 bm x 1 z:
// working set = 8 A-panels (2.36 MB) + 1 B z-slice (1.18 MB) = 3.5 MB < 4 MB L2.
// ---------------------------------------------------------------------------
__global__ __launch_bounds__(512)
void gemm_big(const u16* __restrict__ A, const u16* __restrict__ B,
              float* __restrict__ Cout) {
    constexpr int Kd = 4608, kPerZ = 1152, NT = 512;
    __shared__ u16 As[128][72];
    __shared__ u16 Bs[128][72];

    const int lin = blockIdx.x;
    const int sw  = (lin & 7) * 32 + (lin >> 3);   // bijective on [0,256)
    const int bn = (sw & 3) * 128;
    const int bm = ((sw >> 2) & 15) * 128;
    const int z  = sw >> 6;

    const int tid  = threadIdx.x;
    const int wave = tid >> 6, lane = tid & 63;
    const int wm = (wave >> 2) * 64, wn = (wave & 3) * 32;   // 2x4 wave grid
    const int lr = lane & 15, kh = lane >> 4;

    const u16* Ab = A + (size_t)bm * Kd + z * kPerZ;
    const u16* Bb = B + (size_t)bn * Kd + z * kPerZ;

    f32x4 acc[4][2];
#pragma unroll
    for (int a = 0; a < 4; ++a)
#pragma unroll
        for (int b = 0; b < 2; ++b) acc[a][b] = (f32x4){0.f, 0.f, 0.f, 0.f};

    uint4 ar[2], br[2];
#pragma unroll
    for (int c = 0; c < 2; ++c) {
        int id = tid + c * 512;            // 1024 uint4 per tile
        ar[c] = *reinterpret_cast<const uint4*>(Ab + (size_t)(id >> 3) * Kd + (id & 7) * 8);
        br[c] = *reinterpret_cast<const uint4*>(Bb + (size_t)(id >> 3) * Kd + (id & 7) * 8);
    }

    for (int kt = 0; kt < kPerZ; kt += 64) {
        __syncthreads();
#pragma unroll
        for (int c = 0; c < 2; ++c) {
            int id = tid + c * 512;
            *reinterpret_cast<uint4*>(&As[id >> 3][(id & 7) * 8]) = ar[c];
            *reinterpret_cast<uint4*>(&Bs[id >> 3][(id & 7) * 8]) = br[c];
        }
        __syncthreads();

        if (kt + 64 < kPerZ) {
#pragma unroll
            for (int c = 0; c < 2; ++c) {
                int id = tid + c * 512;
                ar[c] = *reinterpret_cast<const uint4*>(Ab + (size_t)(id >> 3) * Kd + kt + 64 + (id & 7) * 8);
                br[c] = *reinterpret_cast<const uint4*>(Bb + (size_t)(id >> 3) * Kd + kt + 64 + (id & 7) * 8);
            }
        }

#pragma unroll
        for (int ks = 0; ks < 2; ++ks) {
            short8 af[4], bfr[2];
#pragma unroll
            for (int a = 0; a < 4; ++a)
                af[a] = *reinterpret_cast<const short8*>(&As[wm + a * 16 + lr][ks * 32 + kh * 8]);
#pragma unroll
            for (int b = 0; b < 2; ++b)
                bfr[b] = *reinterpret_cast<const short8*>(&Bs[wn + b * 16 + lr][ks * 32 + kh * 8]);
#pragma unroll
            for (int a = 0; a < 4; ++a)
#pragma unroll
                for (int b = 0; b < 2; ++b)
                    acc[a][b] = __builtin_amdgcn_mfma_f32_16x16x32_bf16(af[a], bfr[b], acc[a][b], 0, 0, 0);
        }
    }

    const int r0 = kh * 4;
#pragma unroll
    for (int a = 0; a < 4; ++a)
#pragma unroll
        for (int b = 0; b < 2; ++b)
#pragma unroll
            for (int r = 0; r < 4; ++r) {
                int row = bm + wm + a * 16 + r0 + r;
                int col = bn + wn + b * 16 + lr;
                Cout[((size_t)z * M_ROWS + row) * NT + col] = acc[a][b][r];
            }
}

// ---------------------------------------------------------------------------
// generic bf16 MFMA NT GEMM (hidden N=64 + small GEMMs)
// 256 threads = 4 waves (2x2), BK=64, reg-staged LDS (+8 u16 pad), prefetch.
// EPI 0: f32 store to plane blockIdx.z   EPI 1: bf16 acc + bf16 aux (residual)
// EPI 2: gelu(acc + f32 aux[n]) -> f32/bf16 per OUTF32
// ---------------------------------------------------------------------------
template<int BM, int BN, int EPI, bool OUTF32>
__global__ __launch_bounds__(256)
void gemm_mfma(const u16* __restrict__ A, const u16* __restrict__ B,
               void* __restrict__ Cout, const void* __restrict__ aux,
               int M, int N, int Kd, int kPerZ) {
    constexpr int WSM = BM / 2, WSN = BN / 2;
    constexpr int FM = WSM / 16, FN = WSN / 16;
    constexpr int CA = BM / 32, CB = BN / 32;
    __shared__ u16 As[BM][72];
    __shared__ u16 Bs[BN][72];

    const int tid  = threadIdx.x;
    const int wave = tid >> 6, lane = tid & 63;
    const int wm = (wave >> 1) * WSM, wn = (wave & 1) * WSN;
    const int lr = lane & 15, kh = lane >> 4;
    const int bm = blockIdx.y * BM, bn = blockIdx.x * BN;
    const int k0 = blockIdx.z * kPerZ;

    const u16* Ab = A + (size_t)bm * Kd + k0;
    const u16* Bb = B + (size_t)bn * Kd + k0;

    f32x4 acc[FM][FN];
#pragma unroll
    for (int a = 0; a < FM; ++a)
#pragma unroll
        for (int b = 0; b < FN; ++b) acc[a][b] = (f32x4){0.f, 0.f, 0.f, 0.f};

    uint4 ar[CA], br[CB];
#pragma unroll
    for (int c = 0; c < CA; ++c) {
        int id = tid + c * 256;
        ar[c] = *reinterpret_cast<const uint4*>(Ab + (size_t)(id >> 3) * Kd + (id & 7) * 8);
    }
#pragma unroll
    for (int c = 0; c < CB; ++c) {
        int id = tid + c * 256;
        br[c] = *reinterpret_cast<const uint4*>(Bb + (size_t)(id >> 3) * Kd + (id & 7) * 8);
    }

    for (int kt = 0; kt < kPerZ; kt += 64) {
        __syncthreads();
#pragma unroll
        for (int c = 0; c < CA; ++c) {
            int id = tid + c * 256;
            *reinterpret_cast<uint4*>(&As[id >> 3][(id & 7) * 8]) = ar[c];
        }
#pragma unroll
        for (int c = 0; c < CB; ++c) {
            int id = tid + c * 256;
            *reinterpret_cast<uint4*>(&Bs[id >> 3][(id & 7) * 8]) = br[c];
        }
        __syncthreads();

        if (kt + 64 < kPerZ) {
#pragma unroll
            for (int c = 0; c < CA; ++c) {
                int id = tid + c * 256;
                ar[c] = *reinterpret_cast<const uint4*>(Ab + (size_t)(id >> 3) * Kd + kt + 64 + (id & 7) * 8);
            }
#pragma unroll
            for (int c = 0; c < CB; ++c) {
                int id = tid + c * 256;
                br[c] = *reinterpret_cast<const uint4*>(Bb + (size_t)(id >> 3) * Kd + kt + 64 + (id & 7) * 8);
            }
        }

#pragma unroll
        for (int ks = 0; ks < 2; ++ks) {
            short8 af[FM], bfr[FN];
#pragma unroll
            for (int a = 0; a < FM; ++a)
                af[a] = *reinterpret_cast<const short8*>(&As[wm + a * 16 + lr][ks * 32 + kh * 8]);
#pragma unroll
            for (int b = 0; b < FN; ++b)
                bfr[b] = *reinterpret_cast<const short8*>(&Bs[wn + b * 16 + lr][ks * 32 + kh * 8]);
#pragma unroll
            for (int a = 0; a < FM; ++a)
#pragma unroll
                for (int b = 0; b < FN; ++b)
                    acc[a][b] = __builtin_amdgcn_mfma_f32_16x16x32_bf16(af[a], bfr[b], acc[a][b], 0, 0, 0);
        }
    }

    const int r0 = kh * 4;   // D: row=(lane>>4)*4+reg, col=lane&15
#pragma unroll
    for (int a = 0; a < FM; ++a) {
#pragma unroll
        for (int b = 0; b < FN; ++b) {
#pragma unroll
            for (int r = 0; r < 4; ++r) {
                int row = bm + wm + a * 16 + r0 + r;
                int col = bn + wn + b * 16 + lr;
                float v = acc[a][b][r];
                if (EPI == 0) {
                    ((float*)Cout)[((size_t)blockIdx.z * M + row) * N + col] = v;
                } else if (EPI == 1) {
                    v += bf2f(((const u16*)aux)[(size_t)row * N + col]);
                    ((u16*)Cout)[(size_t)row * N + col] = f2bf(v);
                } else {  // EPI == 2
                    v = geluf(v + ((const float*)aux)[col]);
                    if (OUTF32) ((float*)Cout)[(size_t)row * N + col] = v;
                    else        ((u16*)Cout)[(size_t)row * N + col] = f2bf(v);
                }
            }
        }
    }
}

// ---------------------------------------------------------------------------
// launch
// ---------------------------------------------------------------------------
extern "C" void kernel_launch(void* const* d_in, const int* in_sizes, int n_in,
                              void* d_out, int out_size, void* d_ws, size_t ws_size,
                              hipStream_t stream) {
    const float* x            = (const float*)d_in[0];
    const float* tm1_ln_w     = (const float*)d_in[1];
    const float* tm1_ln_b     = (const float*)d_in[2];
    const float* tm1_k1_base  = (const float*)d_in[3];
    const float* tm1_k1_spl   = (const float*)d_in[4];
    const float* tm1_k2_base  = (const float*)d_in[5];
    const float* tm1_k2_spl   = (const float*)d_in[6];
    const float* g1_w         = (const float*)d_in[8];
    const float* g1_b         = (const float*)d_in[9];
    const float* k1_base      = (const float*)d_in[10];
    const float* k1_spl       = (const float*)d_in[11];
    const float* tm_ln_w      = (const float*)d_in[12];
    const float* tm_ln_b      = (const float*)d_in[13];
    const float* tm_k1_base   = (const float*)d_in[14];
    const float* tm_k1_spl    = (const float*)d_in[15];
    const float* tm_k2_base   = (const float*)d_in[16];
    const float* tm_k2_spl    = (const float*)d_in[17];
    const float* g2_w         = (const float*)d_in[19];
    const float* g2_b         = (const float*)d_in[20];
    const float* k2_base      = (const float*)d_in[21];
    const float* k2_spl       = (const float*)d_in[22];

    float* out = (float*)d_out;

    // ---- workspace layout -------------------------------------------------
    char* w = (char*)d_ws;
    u16*   FEAT  = (u16*)w;   w += (size_t)M_ROWS * 4608 * 2;
    u16*   FEAT2 = (u16*)w;   w += (size_t)M_ROWS * 576 * 2;
    float* PART  = (float*)w; w += (size_t)4 * M_ROWS * 512 * 4;   // also HZ x 2048 x 64
    u16*   XB    = (u16*)w;   w += (size_t)M_ROWS * 512 * 2;
    u16*   BUF1  = (u16*)w;   w += (size_t)M_ROWS * 512 * 2;
    u16*   BUF2  = (u16*)w;   w += (size_t)M_ROWS * 512 * 2;
    u16*   BUF3  = (u16*)w;   w += (size_t)M_ROWS * 512 * 2;
    u16*   W1a   = (u16*)w;   w += (size_t)64 * 4608 * 2;
    u16*   W1b   = (u16*)w;   w += (size_t)64 * 4608 * 2;
    u16*   W2a   = (u16*)w;   w += (size_t)512 * 576 * 2;
    u16*   W2b   = (u16*)w;   w += (size_t)512 * 576 * 2;
    u16*   WE1   = (u16*)w;   w += (size_t)512 * 512 * 2;
    u16*   WE2   = (u16*)w;   w += (size_t)512 * 512 * 2;
    u16*   KX1   = (u16*)w;   w += (size_t)512 * 4608 * 2;
    u16*   KX2   = (u16*)w;   w += (size_t)512 * 4608 * 2;
    float* LNT   = (float*)w; w += (size_t)4 * 65536 * 4;
    float* SR    = (float*)w; w += 64 * 4;
    const float* LNT0w = LNT, *LNT0b = LNT + 65536;
    const float* LNT2w = LNT + 131072, *LNT2b = LNT + 196608;

    // ---- merged prep (weights, LN transpose, stats zeroing) ---------------
    PrepPtrs p;
    p.g1_w = g1_w; p.g2_w = g2_w;
    p.b1 = tm1_k1_base; p.s1 = tm1_k1_spl;
    p.b2 = tm_k1_base;  p.s2 = tm_k1_spl;
    p.b3 = tm1_k2_base; p.s3 = tm1_k2_spl;
    p.b4 = tm_k2_base;  p.s4 = tm_k2_spl;
    p.b5 = k1_base;     p.s5 = k1_spl;
    p.b6 = k2_base;     p.s6 = k2_spl;
    p.WE1 = WE1; p.WE2 = WE2; p.W1a = W1a; p.W1b = W1b;
    p.W2a = W2a; p.W2b = W2b; p.KX1 = KX1; p.KX2 = KX2;
    p.ln1w = tm1_ln_w; p.ln1b = tm1_ln_b; p.ln2w = tm_ln_w; p.ln2b = tm_ln_b;
    p.LNT = LNT; p.SR = SR;
    prep_all<<<5633, 256, 0, stream>>>(p);

    // ---- branch 1: tm1 = token_mixing(x); y1 = gelu(tm1 @ WE1 + b1) -> out
    stats1_convert<<<1024, 256, 0, stream>>>(x, XB, SR);
    build_feat<true, false><<<dim3(2, M_ROWS), 256, 0, stream>>>(x, SR, LNT0w, LNT0b, FEAT);
    gemm_mfma<64, 64, 0, true><<<dim3(1, 32, HZ), 256, 0, stream>>>(FEAT, W1a, PART, nullptr, M_ROWS, 64, 4608, 4608 / HZ);
    build_feat2<<<512, 256, 0, stream>>>(PART, FEAT2);
    gemm_mfma<64, 32, 1, false><<<dim3(16, 32, 1), 256, 0, stream>>>(FEAT2, W2a, BUF1, XB, M_ROWS, 512, 576, 576);
    gemm_mfma<64, 32, 2, true><<<dim3(16, 32, 1), 256, 0, stream>>>(BUF1, WE1, out, g1_b, M_ROWS, 512, 512, 512);

    // ---- branch 2: cm = kan(x); tm = token_mixing(cm); y2; z = kan(y2) ----
    build_feat<false, false><<<dim3(2, M_ROWS), 256, 0, stream>>>(x, nullptr, nullptr, nullptr, FEAT);
    gemm_big<<<256, 512, 0, stream>>>(FEAT, KX1, PART);
    reduce4_bf16_stats<<<1024, 256, 0, stream>>>(PART, BUF2, SR + 32);

    build_feat<true, true><<<dim3(2, M_ROWS), 256, 0, stream>>>(BUF2, SR + 32, LNT2w, LNT2b, FEAT);
    gemm_mfma<64, 64, 0, true><<<dim3(1, 32, HZ), 256, 0, stream>>>(FEAT, W1b, PART, nullptr, M_ROWS, 64, 4608, 4608 / HZ);
    build_feat2<<<512, 256, 0, stream>>>(PART, FEAT2);
    gemm_mfma<64, 32, 1, false><<<dim3(16, 32, 1), 256, 0, stream>>>(FEAT2, W2b, BUF1, BUF2, M_ROWS, 512, 576, 576);
    gemm_mfma<64, 32, 2, false><<<dim3(16, 32, 1), 256, 0, stream>>>(BUF1, WE2, BUF3, g2_b, M_ROWS, 512, 512, 512);

    build_feat<false, true><<<dim3(2, M_ROWS), 256, 0, stream>>>(BUF3, nullptr, nullptr, nullptr, FEAT);
    gemm_big<<<256, 512, 0, stream>>>(FEAT, KX2, PART);
    reduce4_add<<<1024, 256, 0, stream>>>(PART, out);
}